// Round 3
// baseline (1391.793 us; speedup 1.0000x reference)
//
#include <hip/hip_runtime.h>
#include <math.h>

// TVKoopmanMoE: B=4096, C=128, D=32, K=8, R=8, NSEG=3, STEPS=8 each, DT=0.1
//  - w, diag^2 via tiny per-b kernel (kA)
//  - weighted skew sum folded into ONE GEMM: Shat = LHS @ V2 (kB0,kB2)
//  - sum_k w_k L_k L_k^T = Ltil Ltil^T with Ltil = sqrt(w_k)*rawL_k (kL, kLLT)
//  - kC3: TWO WAVES per b (128 thr). Block-triangular expm Taylor ORDER=5 +
//    2 squarings + 8-step propagation; 2x4 reg tiles, pad-36 + 4-word XOR
//    swizzle (<=2-way conflicts), all row reads b64/b128.

#define NSEGC 3
#define BSZ   4096
#define MUC   0.14861455999447191f   /* -ln(0.7)/(0.1*24) */
#define XSC   0.025f                 /* DT / 2^SQ = 0.1/4 */
#define PAD   36
#define XR(r) ((((r) >> 3) & 3) << 2)

__device__ __forceinline__ void ld4(float d[4], const float* p) {
  const float4 v = *(const float4*)p; d[0]=v.x; d[1]=v.y; d[2]=v.z; d[3]=v.w;
}
__device__ __forceinline__ void ld2(float d[2], const float* p) {
  const float2 v = *(const float2*)p; d[0]=v.x; d[1]=v.y;
}
__device__ __forceinline__ void st4(float* p, const float d[4]) {
  *(float4*)p = make_float4(d[0], d[1], d[2], d[3]);
}

// ---------------- kA: gates (softmax(logits/2)) and diag^2 ----------------
__global__ __launch_bounds__(64) void kA(const float* __restrict__ ctx,
    const float* __restrict__ GW, const float* __restrict__ Gb,
    const float* __restrict__ SgW, const float* __restrict__ Sgb,
    float* __restrict__ Wsm, float* __restrict__ Q2) {
  const int b = blockIdx.x, s = blockIdx.y, l = threadIdx.x;
  __shared__ float c[128];
  c[l]      = ctx[(size_t)b*128 + l];
  c[l + 64] = ctx[(size_t)b*128 + 64 + l];
  __syncthreads();
  if (l < 8) {
    float acc = Gb[s*8 + l];
    #pragma unroll 4
    for (int q = 0; q < 128; ++q) acc += c[q] * GW[(size_t)(s*128 + q)*8 + l];
    float li = acc * 0.5f;            // / TEMP (=2)
    float m = li;
    m = fmaxf(m, __shfl_xor(m, 1));
    m = fmaxf(m, __shfl_xor(m, 2));
    m = fmaxf(m, __shfl_xor(m, 4));
    float e = expf(li - m);
    float sum = e;
    sum += __shfl_xor(sum, 1);
    sum += __shfl_xor(sum, 2);
    sum += __shfl_xor(sum, 4);
    Wsm[((size_t)s*BSZ + b)*8 + l] = e / sum;
  } else if (l < 40) {
    const int d = l - 8;
    float acc = Sgb[s*32 + d];
    #pragma unroll 4
    for (int q = 0; q < 128; ++q) acc += c[q] * SgW[(size_t)(s*128 + q)*32 + d];
    float sp = fmaxf(acc, 0.f) + log1pf(expf(-fabsf(acc)));  // stable softplus
    float dg = fminf(sp, 1.0f);
    Q2[((size_t)s*BSZ + b)*32 + d] = dg * dg;
  }
}

// ---------------- kA2: ctxT[c][b] = ctx[b][c] ----------------
__global__ __launch_bounds__(256) void kA2(const float* __restrict__ ctx,
                                           float* __restrict__ ctxT) {
  __shared__ float tile[32][33];
  const int bb = blockIdx.x * 32, cc = blockIdx.y * 32;
  const int tx = threadIdx.x & 31, ty = threadIdx.x >> 5;
  for (int r = ty; r < 32; r += 8) tile[r][tx] = ctx[(size_t)(bb + r)*128 + cc + tx];
  __syncthreads();
  for (int r = ty; r < 32; r += 8) ctxT[(size_t)(cc + r)*BSZ + bb + tx] = tile[tx][r];
}

// ---------------- kB0: V2[s][(k,c)][n] = S_W[c][k,n] - S_W[c][k,nT] ----------------
__global__ __launch_bounds__(256) void kB0(const float* __restrict__ SW,
                                           float* __restrict__ V2) {
  const int kc = blockIdx.x, s = blockIdx.y;
  const int k = kc >> 7, c = kc & 127;
  const float* src = SW + ((size_t)(s*128 + c))*8192 + (size_t)k*1024;
  float* dst = V2 + (size_t)s*1048576 + (size_t)kc*1024;
  for (int n = threadIdx.x; n < 1024; n += 256) {
    const int i = n >> 5, j = n & 31;
    dst[n] = src[n] - src[j*32 + i];
  }
}

// ---------------- kB0b: skewed S_b ----------------
__global__ __launch_bounds__(256) void kB0b(const float* __restrict__ Sb,
                                            float* __restrict__ SBsk) {
  const int k = blockIdx.x, s = blockIdx.y;
  const float* src = Sb + (size_t)s*8192 + (size_t)k*1024;
  for (int n = threadIdx.x; n < 1024; n += 256)
    SBsk[(size_t)(s*8 + k)*1024 + n] = src[n] - src[(n & 31)*32 + (n >> 5)];
}

// ---------------- kB2: AS = (w (x) ctx) @ V2 + bias ----------------
__global__ __launch_bounds__(256) void kB2(const float* __restrict__ ctxT,
    const float* __restrict__ Wsm, const float* __restrict__ V2,
    const float* __restrict__ SB, float* __restrict__ AS) {
  __shared__ float At[32][128];
  __shared__ float Bt[32][128];
  __shared__ float wS[8][128];
  __shared__ float sbS[8][128];
  const int t = threadIdx.x;
  const int nb = blockIdx.x * 128, bb = blockIdx.y * 128, s = blockIdx.z;
  for (int i = t; i < 1024; i += 256) {
    const int k = i >> 7, x = i & 127;
    wS[k][x]  = Wsm[((size_t)s*BSZ + bb + x)*8 + k];
    sbS[k][x] = SB[(size_t)(s*8 + k)*1024 + nb + x];
  }
  float acc[8][8] = {};
  const int b0 = (t >> 4) * 8, n0 = (t & 15) * 8;
  const int qrow = t >> 3, x0 = (t & 7) * 16;
  for (int kc0 = 0; kc0 < 1024; kc0 += 32) {
    const int kseg = kc0 >> 7, cbase = kc0 & 127;
    __syncthreads();
    #pragma unroll
    for (int rep = 0; rep < 4; ++rep) {
      const int x = x0 + rep*4;
      const float4 cv = *(const float4*)&ctxT[(size_t)(cbase + qrow)*BSZ + bb + x];
      const float4 wv = *(const float4*)&wS[kseg][x];
      *(float4*)&At[qrow][x] = make_float4(cv.x*wv.x, cv.y*wv.y, cv.z*wv.z, cv.w*wv.w);
      *(float4*)&Bt[qrow][x] =
        *(const float4*)&V2[(size_t)s*1048576 + (size_t)(kc0 + qrow)*1024 + nb + x];
    }
    __syncthreads();
    #pragma unroll 8
    for (int q = 0; q < 32; ++q) {
      float av[8], bv[8];
      ld4(av, &At[q][b0]); ld4(av + 4, &At[q][b0 + 4]);
      ld4(bv, &Bt[q][n0]); ld4(bv + 4, &Bt[q][n0 + 4]);
      #pragma unroll
      for (int i = 0; i < 8; ++i)
        #pragma unroll
        for (int j = 0; j < 8; ++j) acc[i][j] += av[i] * bv[j];
    }
  }
  #pragma unroll
  for (int k = 0; k < 8; ++k) {
    float wv[8], sv[8];
    ld4(wv, &wS[k][b0]); ld4(wv + 4, &wS[k][b0 + 4]);
    ld4(sv, &sbS[k][n0]); ld4(sv + 4, &sbS[k][n0 + 4]);
    #pragma unroll
    for (int i = 0; i < 8; ++i)
      #pragma unroll
      for (int j = 0; j < 8; ++j) acc[i][j] += wv[i] * sv[j];
  }
  for (int i = 0; i < 8; ++i) {
    float* dst = AS + ((size_t)s*BSZ + bb + b0 + i)*1024 + nb + n0;
    st4(dst, acc[i]); st4(dst + 4, &acc[i][4]);
  }
}

// ---------------- kL: Ltil = (ctx@L_W + L_b)*sqrt(w) ----------------
__global__ __launch_bounds__(256) void kL(const float* __restrict__ ctxT,
    const float* __restrict__ LW, const float* __restrict__ Lb,
    const float* __restrict__ Wsm, float* __restrict__ LT, int s) {
  __shared__ float At[32][128];
  __shared__ float Bt[32][128];
  __shared__ float wsq[8][128];
  const int t = threadIdx.x;
  const int nb = blockIdx.x * 128, bb = blockIdx.y * 128;
  for (int i = t; i < 1024; i += 256) {
    const int k = i >> 7, x = i & 127;
    wsq[k][x] = sqrtf(Wsm[((size_t)s*BSZ + bb + x)*8 + k]);
  }
  float acc[8][8] = {};
  const int b0 = (t >> 4) * 8, n0 = (t & 15) * 8;
  const int qrow = t >> 3, x0 = (t & 7) * 16;
  for (int c0 = 0; c0 < 128; c0 += 32) {
    __syncthreads();
    #pragma unroll
    for (int rep = 0; rep < 4; ++rep) {
      const int x = x0 + rep*4;
      *(float4*)&At[qrow][x] = *(const float4*)&ctxT[(size_t)(c0 + qrow)*BSZ + bb + x];
      *(float4*)&Bt[qrow][x] =
        *(const float4*)&LW[((size_t)(s*128 + c0 + qrow))*2048 + nb + x];
    }
    __syncthreads();
    #pragma unroll 8
    for (int q = 0; q < 32; ++q) {
      float av[8], bv[8];
      ld4(av, &At[q][b0]); ld4(av + 4, &At[q][b0 + 4]);
      ld4(bv, &Bt[q][n0]); ld4(bv + 4, &Bt[q][n0 + 4]);
      #pragma unroll
      for (int i = 0; i < 8; ++i)
        #pragma unroll
        for (int j = 0; j < 8; ++j) acc[i][j] += av[i] * bv[j];
    }
  }
  const int kidx = (nb + n0) >> 8;
  const int dcol = ((nb + n0) >> 3) & 31;
  float lbv[8];
  #pragma unroll
  for (int j = 0; j < 8; ++j) lbv[j] = Lb[(size_t)s*2048 + nb + n0 + j];
  for (int i = 0; i < 8; ++i) {
    const float wv = wsq[kidx][b0 + i];
    float* dst = LT + (size_t)(bb + b0 + i)*2048 + kidx*256 + dcol;
    #pragma unroll
    for (int j = 0; j < 8; ++j) dst[j*32] = (acc[i][j] + lbv[j]) * wv;
  }
}

// ---------------- kLLT: AS -= Ltil Ltil^T  (4 b per block) ----------------
__global__ __launch_bounds__(128) void kLLT(const float* __restrict__ LT,
                                            float* __restrict__ AS, int s) {
  __shared__ float L4[4][64][32];
  const int t = threadIdx.x;
  const int bbase = blockIdx.x * 4;
  {
    float* l4f = &L4[0][0][0];
    const float* src = LT + (size_t)bbase * 2048;
    for (int i = t*4; i < 8192; i += 512)
      *(float4*)&l4f[i] = *(const float4*)&src[i];
  }
  __syncthreads();
  const int b = t >> 5, u = t & 31;
  const int i0 = (u >> 2) * 4, j0 = (u & 3) * 8;
  float acc[4][8] = {};
  #pragma unroll 8
  for (int kr = 0; kr < 64; ++kr) {
    float pa[4], pb[8];
    ld4(pa, &L4[b][kr][i0]);
    ld4(pb, &L4[b][kr][j0]); ld4(pb + 4, &L4[b][kr][j0 + 4]);
    #pragma unroll
    for (int ii = 0; ii < 4; ++ii)
      #pragma unroll
      for (int jj = 0; jj < 8; ++jj) acc[ii][jj] += pa[ii] * pb[jj];
  }
  float* dst = AS + ((size_t)s*BSZ + bbase + b)*1024;
  for (int ii = 0; ii < 4; ++ii) {
    float x[8];
    ld4(x, &dst[(i0+ii)*32 + j0]); ld4(x + 4, &dst[(i0+ii)*32 + j0 + 4]);
    #pragma unroll
    for (int jj = 0; jj < 8; ++jj) x[jj] -= acc[ii][jj];
    st4(&dst[(i0+ii)*32 + j0], x); st4(&dst[(i0+ii)*32 + j0 + 4], &x[4]);
  }
}

// ================= kC3: two waves per b =================
// Logical element (r,c) of a row-form buffer lives at [r][c ^ XR(r)].
// T-form buffer of M stores M^T with the same rule: element (r,c) of M^T at
// [r][c ^ XR(r)]. All reads/writes below apply the XOR consistently.
__device__ __forceinline__ void mm1(const float (*LT)[PAD], const float (*R)[PAD],
                                    float acc[2][4], int r2, int c4) {
  #pragma unroll
  for (int k0 = 0; k0 < 32; k0 += 4) {
    const int xw = XR(k0);
    float af[4][2], bf[4][4];
    #pragma unroll
    for (int j = 0; j < 4; ++j) {
      ld2(af[j], &LT[k0 + j][r2 ^ xw]);
      ld4(bf[j], &R[k0 + j][c4 ^ xw]);
    }
    #pragma unroll
    for (int j = 0; j < 4; ++j)
      #pragma unroll
      for (int i = 0; i < 2; ++i)
        #pragma unroll
        for (int c = 0; c < 4; ++c) acc[i][c] += af[j][i] * bf[j][c];
  }
}
__device__ __forceinline__ void mm2(const float (*LT)[PAD], const float (*R1)[PAD],
                                    const float (*R2)[PAD],
                                    float a1[2][4], float a2[2][4], int r2, int c4) {
  #pragma unroll
  for (int k0 = 0; k0 < 32; k0 += 4) {
    const int xw = XR(k0);
    float af[4][2], b1[4][4], b2[4][4];
    #pragma unroll
    for (int j = 0; j < 4; ++j) {
      ld2(af[j], &LT[k0 + j][r2 ^ xw]);
      ld4(b1[j], &R1[k0 + j][c4 ^ xw]);
      ld4(b2[j], &R2[k0 + j][c4 ^ xw]);
    }
    #pragma unroll
    for (int j = 0; j < 4; ++j)
      #pragma unroll
      for (int i = 0; i < 2; ++i)
        #pragma unroll
        for (int c = 0; c < 4; ++c) {
          a1[i][c] += af[j][i] * b1[j][c];
          a2[i][c] += af[j][i] * b2[j][c];
        }
  }
}
__device__ __forceinline__ void mm2r(const float (*L1T)[PAD], const float (*L2T)[PAD],
                                     const float (*R)[PAD],
                                     float a1[2][4], float a2[2][4], int r2, int c4) {
  #pragma unroll
  for (int k0 = 0; k0 < 32; k0 += 4) {
    const int xw = XR(k0);
    float a1f[4][2], a2f[4][2], bf[4][4];
    #pragma unroll
    for (int j = 0; j < 4; ++j) {
      ld2(a1f[j], &L1T[k0 + j][r2 ^ xw]);
      ld2(a2f[j], &L2T[k0 + j][r2 ^ xw]);
      ld4(bf[j], &R[k0 + j][c4 ^ xw]);
    }
    #pragma unroll
    for (int j = 0; j < 4; ++j)
      #pragma unroll
      for (int i = 0; i < 2; ++i)
        #pragma unroll
        for (int c = 0; c < 4; ++c) {
          a1[i][c] += a1f[j][i] * bf[j][c];
          a2[i][c] += a2f[j][i] * bf[j][c];
        }
  }
}
__device__ __forceinline__ void stR(float (*M)[PAD], const float T[2][4], int r2, int c4) {
  const int xw = XR(r2);
  st4(&M[r2][c4 ^ xw], T[0]);
  st4(&M[r2 + 1][c4 ^ xw], T[1]);
}
__device__ __forceinline__ void stT(float (*M)[PAD], const float T[2][4], int r2, int c4) {
  const int xw = XR(c4);
  #pragma unroll
  for (int j = 0; j < 4; ++j)
    *(float2*)&M[c4 + j][r2 ^ xw] = make_float2(T[0][j], T[1][j]);
}
__device__ __forceinline__ void ldRow(float d[4], const float (*M)[PAD], int r, int c4) {
  ld4(d, &M[r][c4 ^ XR(r)]);
}

__global__ __launch_bounds__(128) void kC3(const float* __restrict__ AS,
    const float* __restrict__ Q2, const float* __restrict__ z0,
    float* __restrict__ out) {
  __shared__ float b_a[32][PAD], b_at[32][PAD];   // a,aT; later R11T(PhiT),R12T
  __shared__ float b_r11[32][PAD], b_r12[32][PAD], b_r22[32][PAD];
  __shared__ float b_x[32][PAD];                  // R22T; later transpose scratch
  __shared__ float b_cov[32][PAD];
  __shared__ float zarr[32], qds[32], red[2];
  const int b = blockIdx.x, t = threadIdx.x;
  const int u = t & 63, w = t >> 6;
  const int r2 = w*16 + (u >> 3)*2;
  const int c4 = (u & 7)*4;

  if (t < 32) zarr[t] = z0[(size_t)b*32 + t];
  {
    const float zz[2][4] = {{0,0,0,0},{0,0,0,0}};
    stR(b_cov, zz, r2, c4);
  }
  __syncthreads();

  float* covout = out + 3145728 + (size_t)b*24576;
  float* stout  = out + (size_t)b*768;

  for (int s = 0; s < NSEGC; ++s) {
    // ---- load A tile, frob clamp, scale, write a/aT, init R ----
    if (t < 32) qds[t] = Q2[((size_t)s*BSZ + b)*32 + t] * XSC;
    const float* asb = AS + ((size_t)s*BSZ + b)*1024;
    float Atile[2][4];
    ld4(Atile[0], &asb[r2*32 + c4]);
    ld4(Atile[1], &asb[(r2 + 1)*32 + c4]);
    #pragma unroll
    for (int i = 0; i < 2; ++i)
      #pragma unroll
      for (int j = 0; j < 4; ++j) if (r2 + i == c4 + j) Atile[i][j] -= MUC;
    float ssq = 0.f;
    #pragma unroll
    for (int i = 0; i < 2; ++i)
      #pragma unroll
      for (int j = 0; j < 4; ++j) ssq += Atile[i][j]*Atile[i][j];
    #pragma unroll
    for (int off = 1; off < 64; off <<= 1) ssq += __shfl_xor(ssq, off);
    if (u == 0) red[w] = ssq;
    __syncthreads();
    const float frob = sqrtf(red[0] + red[1]);
    const float sc = (frob > 3.0f ? 3.0f / (frob + 1e-6f) : 1.0f) * XSC;
    float av[2][4], id[2][4], zo[2][4];
    #pragma unroll
    for (int i = 0; i < 2; ++i)
      #pragma unroll
      for (int j = 0; j < 4; ++j) {
        av[i][j] = Atile[i][j] * sc;
        id[i][j] = (r2 + i == c4 + j) ? 1.f : 0.f;
        zo[i][j] = 0.f;
      }
    __syncthreads();
    stR(b_a, av, r2, c4);  stT(b_at, av, r2, c4);
    stR(b_r11, id, r2, c4); stR(b_r22, id, r2, c4); stR(b_r12, zo, r2, c4);
    __syncthreads();

    // ---- Taylor Horner ORDER=5: R = I + X@R/k ----
    #pragma unroll
    for (int k = 5; k >= 1; --k) {
      float A11[2][4] = {}, A12[2][4] = {}, A22[2][4] = {};
      mm2(b_at, b_r11, b_r12, A11, A12, r2, c4);   // a@R11, a@R12
      mm1(b_a, b_r22, A22, r2, c4);                 // a^T@R22
      #pragma unroll
      for (int i = 0; i < 2; ++i) {                 // + q@R22 (diag row-scale)
        float rv[4]; ldRow(rv, b_r22, r2 + i, c4);
        const float qv = qds[r2 + i];
        #pragma unroll
        for (int c = 0; c < 4; ++c) A12[i][c] += qv * rv[c];
      }
      const float rk = 1.0f / (float)k;
      #pragma unroll
      for (int i = 0; i < 2; ++i)
        #pragma unroll
        for (int c = 0; c < 4; ++c) {
          const float e = (r2 + i == c4 + c) ? 1.f : 0.f;
          A11[i][c] = A11[i][c]*rk + e;
          A12[i][c] = A12[i][c]*rk;
          A22[i][c] = e - A22[i][c]*rk;             // I + (-a^T@R22)/k
        }
      __syncthreads();
      stR(b_r11, A11, r2, c4); stR(b_r12, A12, r2, c4); stR(b_r22, A22, r2, c4);
      if (k == 1) {  // T-copies for squaring: R11T->b_a, R12T->b_at, R22T->b_x
        stT(b_a, A11, r2, c4); stT(b_at, A12, r2, c4); stT(b_x, A22, r2, c4);
      }
      __syncthreads();
    }

    // ---- 2 squarings (block upper-triangular) ----
    #pragma unroll
    for (int sq = 0; sq < 2; ++sq) {
      float A11[2][4] = {}, A12[2][4] = {}, A22[2][4] = {};
      mm2(b_a, b_r11, b_r12, A11, A12, r2, c4);    // R11@R11, R11@R12
      mm2r(b_at, b_x, b_r22, A12, A22, r2, c4);    // +R12@R22, R22@R22
      __syncthreads();
      stR(b_r11, A11, r2, c4); stT(b_a, A11, r2, c4);
      stR(b_r12, A12, r2, c4); stT(b_at, A12, r2, c4);
      stR(b_r22, A22, r2, c4); stT(b_x, A22, r2, c4);
      __syncthreads();
    }

    // ---- Qd = 0.5*(Phi@E12 + (Phi@E12)^T) -> b_r22 ----
    {
      float QA[2][4] = {};
      mm1(b_a, b_r12, QA, r2, c4);                  // Phi@E12 (left PhiT=b_a)
      __syncthreads();
      stT(b_x, QA, r2, c4);
      __syncthreads();
      float qd_[2][4];
      #pragma unroll
      for (int i = 0; i < 2; ++i) {
        float ct[4]; ldRow(ct, b_x, r2 + i, c4);
        #pragma unroll
        for (int c = 0; c < 4; ++c) qd_[i][c] = 0.5f * (QA[i][c] + ct[c]);
      }
      __syncthreads();
      stR(b_r22, qd_, r2, c4);
      __syncthreads();
    }

    // ---- 8 propagation steps ----
    for (int tt = 0; tt < 8; ++tt) {
      float T1[2][4] = {};
      mm1(b_a, b_cov, T1, r2, c4);                  // T1 = Phi@cov
      __syncthreads();
      stT(b_at, T1, r2, c4);                        // T1T (E12T dead)
      __syncthreads();
      float Cc[2][4] = {};
      mm1(b_at, b_a, Cc, r2, c4);                   // Cc = T1@Phi^T
      // z' = Phi@z on wave 0 (rows from b_r11)
      float zp = 0.f;
      if (t < 64) {
        const int zr = t & 31, zh = (t >> 5) * 16;
        #pragma unroll
        for (int q4 = 0; q4 < 4; ++q4) {
          float pv[4], zz[4];
          ld4(pv, &b_r11[zr][(zh + q4*4) ^ XR(zr)]);
          ld4(zz, &zarr[zh + q4*4]);
          #pragma unroll
          for (int e = 0; e < 4; ++e) zp += pv[e] * zz[e];
        }
        zp += __shfl_xor(zp, 32);
      }
      __syncthreads();
      stT(b_x, Cc, r2, c4);
      __syncthreads();
      float cv[2][4];
      #pragma unroll
      for (int i = 0; i < 2; ++i) {
        float ct[4], qv[4];
        ldRow(ct, b_x, r2 + i, c4);
        ldRow(qv, b_r22, r2 + i, c4);
        #pragma unroll
        for (int c = 0; c < 4; ++c) cv[i][c] = 0.5f * (Cc[i][c] + ct[c]) + qv[c];
      }
      __syncthreads();
      stR(b_cov, cv, r2, c4);
      float* cb = covout + (size_t)(s*8 + tt)*1024;
      st4(&cb[r2*32 + c4], cv[0]);
      st4(&cb[(r2 + 1)*32 + c4], cv[1]);
      if (t < 32) {
        zarr[t] = zp;
        stout[(s*8 + tt)*32 + t] = zp;
      }
      __syncthreads();
    }
  }
}

// ---------------- launch ----------------
extern "C" void kernel_launch(void* const* d_in, const int* in_sizes, int n_in,
                              void* d_out, int out_size, void* d_ws, size_t ws_size,
                              hipStream_t stream) {
  const float* ctx  = (const float*)d_in[0];
  const float* z0   = (const float*)d_in[1];
  const float* S_W  = (const float*)d_in[2];
  const float* S_b  = (const float*)d_in[3];
  const float* L_W  = (const float*)d_in[4];
  const float* L_b  = (const float*)d_in[5];
  const float* G_W  = (const float*)d_in[6];
  const float* G_b  = (const float*)d_in[7];
  const float* Sg_W = (const float*)d_in[8];
  const float* Sg_b = (const float*)d_in[9];
  float* out = (float*)d_out;
  float* ws  = (float*)d_ws;

  float* w_   = ws;                 // [3][4096][8]
  float* q2   = ws + 98304;         // [3][4096][32]
  float* ctxT = ws + 491520;        // [128][4096]
  float* sbsk = ws + 1015808;       // [3][8][1024]
  float* v2   = ws + 1040384;       // [3][1024][1024]
  float* as_  = ws + 4186112;       // [3][4096][1024]
  float* lt   = ws + 16769024;      // [4096][2048] (per-seg reuse)

  kA  <<<dim3(4096, 3), 64,  0, stream>>>(ctx, G_W, G_b, Sg_W, Sg_b, w_, q2);
  kA2 <<<dim3(128, 4),  256, 0, stream>>>(ctx, ctxT);
  kB0 <<<dim3(1024, 3), 256, 0, stream>>>(S_W, v2);
  kB0b<<<dim3(8, 3),    256, 0, stream>>>(S_b, sbsk);
  kB2 <<<dim3(8, 32, 3),256, 0, stream>>>(ctxT, w_, v2, sbsk, as_);
  for (int s = 0; s < 3; ++s) {
    kL  <<<dim3(16, 32), 256, 0, stream>>>(ctxT, L_W, L_b, w_, lt, s);
    kLLT<<<dim3(1024),   128, 0, stream>>>(lt, as_, s);
  }
  kC3 <<<dim3(4096),    128, 0, stream>>>(as_, q2, z0, out);
}

// Round 5
// 882.865 us; speedup vs baseline: 1.5764x; 1.5764x over previous
//
#include <hip/hip_runtime.h>
#include <math.h>

// TVKoopmanMoE: B=4096, C=128, D=32, K=8, R=8, NSEG=3, STEPS=8 each, DT=0.1
//  - w, diag^2 via tiny per-b kernel (kA)
//  - weighted skew sum folded into ONE GEMM: Shat = LHS @ V2 (kB0,kB2)
//  - sum_k w_k L_k L_k^T = Ltil Ltil^T with Ltil = sqrt(w_k)*rawL_k (kL, kLLT)
//  - kC5: ONE WAVE per b. All 32x32 matmuls via v_mfma_f32_32x32x16_bf16 with
//    hi/lo fp32->bf16 split (3 mfma per K=16 chunk). Matrices live in LDS fp32
//    [32][32] with XOR swizzle c^=(r&7)<<2. Taylor tracks TRANSPOSED blocks so
//    every matmul is P@Q^T (A-frag = P rows, B-frag = Q rows) and every store
//    is the cheap C/D-transpose store. Phi/a fragments cached in VGPRs.
//    Qd = 0.5*(Phi@E12 + (Phi@E12)^T)  -- symmetrization REQUIRED (O(dt^2)
//    asymmetry for M=[[A,Q],[0,-A^T]]), done via transpose readback.

#define NSEGC 3
#define BSZ   4096
#define MUC   0.14861455999447191f   /* -ln(0.7)/(0.1*24) */
#define XSC   0.025f                 /* DT / 2^SQ = 0.1/4 */
#define XRS(r) (((r) & 7) << 2)

typedef __attribute__((ext_vector_type(8))) short bf16x8;
typedef __attribute__((ext_vector_type(16))) float f32x16;

__device__ __forceinline__ void ld4(float d[4], const float* p) {
  const float4 v = *(const float4*)p; d[0]=v.x; d[1]=v.y; d[2]=v.z; d[3]=v.w;
}
__device__ __forceinline__ void st4(float* p, const float d[4]) {
  *(float4*)p = make_float4(d[0], d[1], d[2], d[3]);
}

// ---------------- kA: gates (softmax(logits/2)) and diag^2 ----------------
__global__ __launch_bounds__(64) void kA(const float* __restrict__ ctx,
    const float* __restrict__ GW, const float* __restrict__ Gb,
    const float* __restrict__ SgW, const float* __restrict__ Sgb,
    float* __restrict__ Wsm, float* __restrict__ Q2) {
  const int b = blockIdx.x, s = blockIdx.y, l = threadIdx.x;
  __shared__ float c[128];
  c[l]      = ctx[(size_t)b*128 + l];
  c[l + 64] = ctx[(size_t)b*128 + 64 + l];
  __syncthreads();
  if (l < 8) {
    float acc = Gb[s*8 + l];
    #pragma unroll 4
    for (int q = 0; q < 128; ++q) acc += c[q] * GW[(size_t)(s*128 + q)*8 + l];
    float li = acc * 0.5f;            // / TEMP (=2)
    float m = li;
    m = fmaxf(m, __shfl_xor(m, 1));
    m = fmaxf(m, __shfl_xor(m, 2));
    m = fmaxf(m, __shfl_xor(m, 4));
    float e = expf(li - m);
    float sum = e;
    sum += __shfl_xor(sum, 1);
    sum += __shfl_xor(sum, 2);
    sum += __shfl_xor(sum, 4);
    Wsm[((size_t)s*BSZ + b)*8 + l] = e / sum;
  } else if (l < 40) {
    const int d = l - 8;
    float acc = Sgb[s*32 + d];
    #pragma unroll 4
    for (int q = 0; q < 128; ++q) acc += c[q] * SgW[(size_t)(s*128 + q)*32 + d];
    float sp = fmaxf(acc, 0.f) + log1pf(expf(-fabsf(acc)));  // stable softplus
    float dg = fminf(sp, 1.0f);
    Q2[((size_t)s*BSZ + b)*32 + d] = dg * dg;
  }
}

// ---------------- kA2: ctxT[c][b] = ctx[b][c] ----------------
__global__ __launch_bounds__(256) void kA2(const float* __restrict__ ctx,
                                           float* __restrict__ ctxT) {
  __shared__ float tile[32][33];
  const int bb = blockIdx.x * 32, cc = blockIdx.y * 32;
  const int tx = threadIdx.x & 31, ty = threadIdx.x >> 5;
  for (int r = ty; r < 32; r += 8) tile[r][tx] = ctx[(size_t)(bb + r)*128 + cc + tx];
  __syncthreads();
  for (int r = ty; r < 32; r += 8) ctxT[(size_t)(cc + r)*BSZ + bb + tx] = tile[tx][r];
}

// ---------------- kB0: V2[s][(k,c)][n] = S_W[c][k,n] - S_W[c][k,nT] ----------------
__global__ __launch_bounds__(256) void kB0(const float* __restrict__ SW,
                                           float* __restrict__ V2) {
  const int kc = blockIdx.x, s = blockIdx.y;
  const int k = kc >> 7, c = kc & 127;
  const float* src = SW + ((size_t)(s*128 + c))*8192 + (size_t)k*1024;
  float* dst = V2 + (size_t)s*1048576 + (size_t)kc*1024;
  for (int n = threadIdx.x; n < 1024; n += 256) {
    const int i = n >> 5, j = n & 31;
    dst[n] = src[n] - src[j*32 + i];
  }
}

// ---------------- kB0b: skewed S_b ----------------
__global__ __launch_bounds__(256) void kB0b(const float* __restrict__ Sb,
                                            float* __restrict__ SBsk) {
  const int k = blockIdx.x, s = blockIdx.y;
  const float* src = Sb + (size_t)s*8192 + (size_t)k*1024;
  for (int n = threadIdx.x; n < 1024; n += 256)
    SBsk[(size_t)(s*8 + k)*1024 + n] = src[n] - src[(n & 31)*32 + (n >> 5)];
}

// ---------------- kB2: AS = (w (x) ctx) @ V2 + bias ----------------
__global__ __launch_bounds__(256) void kB2(const float* __restrict__ ctxT,
    const float* __restrict__ Wsm, const float* __restrict__ V2,
    const float* __restrict__ SB, float* __restrict__ AS) {
  __shared__ float At[32][128];
  __shared__ float Bt[32][128];
  __shared__ float wS[8][128];
  __shared__ float sbS[8][128];
  const int t = threadIdx.x;
  const int nb = blockIdx.x * 128, bb = blockIdx.y * 128, s = blockIdx.z;
  for (int i = t; i < 1024; i += 256) {
    const int k = i >> 7, x = i & 127;
    wS[k][x]  = Wsm[((size_t)s*BSZ + bb + x)*8 + k];
    sbS[k][x] = SB[(size_t)(s*8 + k)*1024 + nb + x];
  }
  float acc[8][8] = {};
  const int b0 = (t >> 4) * 8, n0 = (t & 15) * 8;
  const int qrow = t >> 3, x0 = (t & 7) * 16;
  for (int kc0 = 0; kc0 < 1024; kc0 += 32) {
    const int kseg = kc0 >> 7, cbase = kc0 & 127;
    __syncthreads();
    #pragma unroll
    for (int rep = 0; rep < 4; ++rep) {
      const int x = x0 + rep*4;
      const float4 cv = *(const float4*)&ctxT[(size_t)(cbase + qrow)*BSZ + bb + x];
      const float4 wv = *(const float4*)&wS[kseg][x];
      *(float4*)&At[qrow][x] = make_float4(cv.x*wv.x, cv.y*wv.y, cv.z*wv.z, cv.w*wv.w);
      *(float4*)&Bt[qrow][x] =
        *(const float4*)&V2[(size_t)s*1048576 + (size_t)(kc0 + qrow)*1024 + nb + x];
    }
    __syncthreads();
    #pragma unroll 8
    for (int q = 0; q < 32; ++q) {
      float av[8], bv[8];
      ld4(av, &At[q][b0]); ld4(av + 4, &At[q][b0 + 4]);
      ld4(bv, &Bt[q][n0]); ld4(bv + 4, &Bt[q][n0 + 4]);
      #pragma unroll
      for (int i = 0; i < 8; ++i)
        #pragma unroll
        for (int j = 0; j < 8; ++j) acc[i][j] += av[i] * bv[j];
    }
  }
  #pragma unroll
  for (int k = 0; k < 8; ++k) {
    float wv[8], sv[8];
    ld4(wv, &wS[k][b0]); ld4(wv + 4, &wS[k][b0 + 4]);
    ld4(sv, &sbS[k][n0]); ld4(sv + 4, &sbS[k][n0 + 4]);
    #pragma unroll
    for (int i = 0; i < 8; ++i)
      #pragma unroll
      for (int j = 0; j < 8; ++j) acc[i][j] += wv[i] * sv[j];
  }
  for (int i = 0; i < 8; ++i) {
    float* dst = AS + ((size_t)s*BSZ + bb + b0 + i)*1024 + nb + n0;
    st4(dst, acc[i]); st4(dst + 4, &acc[i][4]);
  }
}

// ---------------- kL: Ltil = (ctx@L_W + L_b)*sqrt(w) ----------------
__global__ __launch_bounds__(256) void kL(const float* __restrict__ ctxT,
    const float* __restrict__ LW, const float* __restrict__ Lb,
    const float* __restrict__ Wsm, float* __restrict__ LT, int s) {
  __shared__ float At[32][128];
  __shared__ float Bt[32][128];
  __shared__ float wsq[8][128];
  const int t = threadIdx.x;
  const int nb = blockIdx.x * 128, bb = blockIdx.y * 128;
  for (int i = t; i < 1024; i += 256) {
    const int k = i >> 7, x = i & 127;
    wsq[k][x] = sqrtf(Wsm[((size_t)s*BSZ + bb + x)*8 + k]);
  }
  float acc[8][8] = {};
  const int b0 = (t >> 4) * 8, n0 = (t & 15) * 8;
  const int qrow = t >> 3, x0 = (t & 7) * 16;
  for (int c0 = 0; c0 < 128; c0 += 32) {
    __syncthreads();
    #pragma unroll
    for (int rep = 0; rep < 4; ++rep) {
      const int x = x0 + rep*4;
      *(float4*)&At[qrow][x] = *(const float4*)&ctxT[(size_t)(c0 + qrow)*BSZ + bb + x];
      *(float4*)&Bt[qrow][x] =
        *(const float4*)&LW[((size_t)(s*128 + c0 + qrow))*2048 + nb + x];
    }
    __syncthreads();
    #pragma unroll 8
    for (int q = 0; q < 32; ++q) {
      float av[8], bv[8];
      ld4(av, &At[q][b0]); ld4(av + 4, &At[q][b0 + 4]);
      ld4(bv, &Bt[q][n0]); ld4(bv + 4, &Bt[q][n0 + 4]);
      #pragma unroll
      for (int i = 0; i < 8; ++i)
        #pragma unroll
        for (int j = 0; j < 8; ++j) acc[i][j] += av[i] * bv[j];
    }
  }
  const int kidx = (nb + n0) >> 8;
  const int dcol = ((nb + n0) >> 3) & 31;
  float lbv[8];
  #pragma unroll
  for (int j = 0; j < 8; ++j) lbv[j] = Lb[(size_t)s*2048 + nb + n0 + j];
  for (int i = 0; i < 8; ++i) {
    const float wv = wsq[kidx][b0 + i];
    float* dst = LT + (size_t)(bb + b0 + i)*2048 + kidx*256 + dcol;
    #pragma unroll
    for (int j = 0; j < 8; ++j) dst[j*32] = (acc[i][j] + lbv[j]) * wv;
  }
}

// ---------------- kLLT: AS -= Ltil Ltil^T  (4 b per block) ----------------
__global__ __launch_bounds__(128) void kLLT(const float* __restrict__ LT,
                                            float* __restrict__ AS, int s) {
  __shared__ float L4[4][64][32];
  const int t = threadIdx.x;
  const int bbase = blockIdx.x * 4;
  {
    float* l4f = &L4[0][0][0];
    const float* src = LT + (size_t)bbase * 2048;
    for (int i = t*4; i < 8192; i += 512)
      *(float4*)&l4f[i] = *(const float4*)&src[i];
  }
  __syncthreads();
  const int b = t >> 5, u = t & 31;
  const int i0 = (u >> 2) * 4, j0 = (u & 3) * 8;
  float acc[4][8] = {};
  #pragma unroll 8
  for (int kr = 0; kr < 64; ++kr) {
    float pa[4], pb[8];
    ld4(pa, &L4[b][kr][i0]);
    ld4(pb, &L4[b][kr][j0]); ld4(pb + 4, &L4[b][kr][j0 + 4]);
    #pragma unroll
    for (int ii = 0; ii < 4; ++ii)
      #pragma unroll
      for (int jj = 0; jj < 8; ++jj) acc[ii][jj] += pa[ii] * pb[jj];
  }
  float* dst = AS + ((size_t)s*BSZ + bbase + b)*1024;
  for (int ii = 0; ii < 4; ++ii) {
    float x[8];
    ld4(x, &dst[(i0+ii)*32 + j0]); ld4(x + 4, &dst[(i0+ii)*32 + j0 + 4]);
    #pragma unroll
    for (int jj = 0; jj < 8; ++jj) x[jj] -= acc[ii][jj];
    st4(&dst[(i0+ii)*32 + j0], x); st4(&dst[(i0+ii)*32 + j0 + 4], &x[4]);
  }
}

// ================= kC5: MFMA hi/lo expm + propagation, one wave per b =========
// Storage: matrix M in LDS fp32 [32][32], element (r,c) at [r][c ^ XRS(r)].
// Convention: each buffer stores X^T for its logical matrix X.
// MM(P,Q) = P@Q^T: A-frag lane l = P[l&31][8*(l>>5)+e] (+16 for chunk1),
//                  B-frag lane l = Q[l&31][8*(l>>5)+e].
// C/D: col = lane&31, row = (reg&3) + 8*(reg>>2) + 4*(lane>>5).
// st_T stores OUT^T (cheap C/D store), maintaining the convention.

struct Frag { bf16x8 h0, l0, h1, l1; };

__device__ __forceinline__ unsigned short bf_rne(float x) {
  unsigned b = __float_as_uint(x);
  unsigned r = b + 0x7FFFu + ((b >> 16) & 1u);
  return (unsigned short)(r >> 16);
}
__device__ __forceinline__ void cvt8(const float x[8], bf16x8& hi, bf16x8& lo) {
  #pragma unroll
  for (int e = 0; e < 8; ++e) {
    unsigned short h = bf_rne(x[e]);
    float hf = __uint_as_float(((unsigned)h) << 16);
    float l = x[e] - hf;                 // exact
    hi[e] = (short)h;
    lo[e] = (short)bf_rne(l);
  }
}
__device__ __forceinline__ void rd_row8(const float* M, int r, int kb, float o[8]) {
  const float* p = M + r*32;
  ld4(o,     p + ((kb)     ^ XRS(r)));
  ld4(o + 4, p + ((kb + 4) ^ XRS(r)));
}
__device__ __forceinline__ void rd_col8(const float* M, int c, int kb, float o[8]) {
  #pragma unroll
  for (int e = 0; e < 8; ++e) o[e] = M[(kb + e)*32 + (c ^ XRS(kb + e))];
}
__device__ __forceinline__ void mkfrag_row(const float* M, int r, int hoff, Frag& f) {
  float t0[8], t1[8];
  rd_row8(M, r, hoff, t0);
  rd_row8(M, r, 16 + hoff, t1);
  cvt8(t0, f.h0, f.l0);
  cvt8(t1, f.h1, f.l1);
}
__device__ __forceinline__ void mkfrag_col(const float* M, int c, int hoff, Frag& f) {
  float t0[8], t1[8];
  rd_col8(M, c, hoff, t0);
  rd_col8(M, c, 16 + hoff, t1);
  cvt8(t0, f.h0, f.l0);
  cvt8(t1, f.h1, f.l1);
}
__device__ __forceinline__ f32x16 mmacc(const Frag& A, const Frag& B, f32x16 acc) {
  acc = __builtin_amdgcn_mfma_f32_32x32x16_bf16(A.h0, B.h0, acc, 0, 0, 0);
  acc = __builtin_amdgcn_mfma_f32_32x32x16_bf16(A.h0, B.l0, acc, 0, 0, 0);
  acc = __builtin_amdgcn_mfma_f32_32x32x16_bf16(A.l0, B.h0, acc, 0, 0, 0);
  acc = __builtin_amdgcn_mfma_f32_32x32x16_bf16(A.h1, B.h1, acc, 0, 0, 0);
  acc = __builtin_amdgcn_mfma_f32_32x32x16_bf16(A.h1, B.l1, acc, 0, 0, 0);
  acc = __builtin_amdgcn_mfma_f32_32x32x16_bf16(A.l1, B.h1, acc, 0, 0, 0);
  return acc;
}
__device__ __forceinline__ f32x16 zero16() {
  f32x16 z = {0.f,0.f,0.f,0.f,0.f,0.f,0.f,0.f,0.f,0.f,0.f,0.f,0.f,0.f,0.f,0.f};
  return z;
}
// store OUT^T into M (from float[16] in C/D order)
__device__ __forceinline__ void st_T(float* M, int j, int ho4, const float v[16]) {
  float* p = M + j*32;
  #pragma unroll
  for (int m = 0; m < 4; ++m) st4(p + ((8*m + ho4) ^ XRS(j)), v + 4*m);
}
// read back what st_T stored: o[r] = buffer[j][row(r)]
__device__ __forceinline__ void ld16_T(const float* M, int j, int ho4, float o[16]) {
  const float* p = M + j*32;
  #pragma unroll
  for (int m = 0; m < 4; ++m) ld4(o + 4*m, p + ((8*m + ho4) ^ XRS(j)));
}

__global__ __launch_bounds__(64) void kC5(const float* __restrict__ AS,
    const float* __restrict__ Q2, const float* __restrict__ z0,
    float* __restrict__ out) {
  __shared__ float SA[1024];   // a ; later G scratch
  __shared__ float S11[1024];  // R11^T (Phi^T after squaring)
  __shared__ float S12[1024];  // R12^T (E12^T)
  __shared__ float S22[1024];  // R22^T ; later Qd
  __shared__ float SCV[1024];  // cov (symmetric)
  __shared__ float zarr[32], qds[32];
  const int b = blockIdx.x, t = threadIdx.x;
  const int j = t & 31, hh = t >> 5;
  const int hoff = hh * 8, ho4 = hh * 4;

  if (t < 32) zarr[t] = z0[(size_t)b*32 + t];
  for (int i = t; i < 1024; i += 64) SCV[i] = 0.f;
  __syncthreads();

  float* covout = out + 3145728 + (size_t)b*24576;
  float* stout  = out + (size_t)b*768;

  for (int s = 0; s < NSEGC; ++s) {
    // ---------- init: load A, -muI, frob clamp, scale; a, t11=I, t12=0, t22=I --
    if (t < 32) qds[t] = Q2[((size_t)s*BSZ + b)*32 + t] * XSC;
    const float* asb = AS + ((size_t)s*BSZ + b)*1024;
    float av[16];
    #pragma unroll
    for (int m = 0; m < 4; ++m) ld4(av + 4*m, &asb[j*32 + 16*hh + 4*m]);
    #pragma unroll
    for (int i = 0; i < 16; ++i) if (16*hh + i == j) av[i] -= MUC;
    float ssq = 0.f;
    #pragma unroll
    for (int i = 0; i < 16; ++i) ssq += av[i]*av[i];
    #pragma unroll
    for (int off = 1; off < 64; off <<= 1) ssq += __shfl_xor(ssq, off);
    const float frob = sqrtf(ssq);
    const float sc = (frob > 3.0f ? 3.0f / (frob + 1e-6f) : 1.0f) * XSC;
    #pragma unroll
    for (int i = 0; i < 16; ++i) av[i] *= sc;
    #pragma unroll
    for (int m = 0; m < 4; ++m) {
      st4(&SA[j*32 + ((16*hh + 4*m) ^ XRS(j))], av + 4*m);
      float id[4], zo[4] = {0.f, 0.f, 0.f, 0.f};
      #pragma unroll
      for (int e = 0; e < 4; ++e) id[e] = (16*hh + 4*m + e == j) ? 1.f : 0.f;
      st4(&S11[j*32 + ((16*hh + 4*m) ^ XRS(j))], id);
      st4(&S22[j*32 + ((16*hh + 4*m) ^ XRS(j))], id);
      st4(&S12[j*32 + ((16*hh + 4*m) ^ XRS(j))], zo);
    }
    __syncthreads();
    float qv[16];
    #pragma unroll
    for (int r = 0; r < 16; ++r) qv[r] = qds[(r&3) + 8*(r>>2) + ho4];
    Frag aA, aT;
    mkfrag_row(SA, j, hoff, aA);   // A-frag of a
    mkfrag_col(SA, j, hoff, aT);   // A-frag of a^T

    // ---------- Taylor Horner ORDER=5 on X=[[a,q],[0,-a^T]] (transposed blocks)
    for (int k = 5; k >= 1; --k) {
      const float rk = 1.0f / (float)k;
      Frag Bf;
      float Xs[16];
      // R11' = I + a@R11/k  (B-frag of R11 = row-read of S11=R11^T)
      mkfrag_row(S11, j, hoff, Bf);
      f32x16 X = mmacc(aA, Bf, zero16());
      #pragma unroll
      for (int r = 0; r < 16; ++r) {
        const int row = (r&3) + 8*(r>>2) + ho4;
        Xs[r] = X[r]*rk + (row == j ? 1.f : 0.f);
      }
      st_T(S11, j, ho4, Xs);
      // R12' = (a@R12 + q@R22)/k
      mkfrag_row(S12, j, hoff, Bf);
      X = mmacc(aA, Bf, zero16());
      float rv[16];
      ld16_T(S22, j, ho4, rv);     // R22[row][j]
      #pragma unroll
      for (int r = 0; r < 16; ++r) Xs[r] = (X[r] + qv[r]*rv[r]) * rk;
      st_T(S12, j, ho4, Xs);
      // R22' = I - a^T@R22/k
      mkfrag_row(S22, j, hoff, Bf);
      X = mmacc(aT, Bf, zero16());
      #pragma unroll
      for (int r = 0; r < 16; ++r) {
        const int row = (r&3) + 8*(r>>2) + ho4;
        Xs[r] = (row == j ? 1.f : 0.f) - X[r]*rk;
      }
      st_T(S22, j, ho4, Xs);
    }
    __syncthreads();

    // ---------- squaring 0: R11<-R11@R11, R12<-R11@R12+R12@R22, R22<-R22@R22 --
    {
      Frag Ac, Br;
      float Xs[16];
      mkfrag_col(S11, j, hoff, Ac);          // A-frag of R11
      mkfrag_row(S11, j, hoff, Br);          // B-frag (Q=R11^T stored)
      f32x16 X1 = mmacc(Ac, Br, zero16());
      #pragma unroll
      for (int r = 0; r < 16; ++r) Xs[r] = X1[r];
      st_T(S11, j, ho4, Xs);                 // all S11 reads done
      Frag B12; mkfrag_row(S12, j, hoff, B12);
      f32x16 X2 = mmacc(Ac, B12, zero16());
      Frag A12; mkfrag_col(S12, j, hoff, A12);
      Frag B22; mkfrag_row(S22, j, hoff, B22);
      X2 = mmacc(A12, B22, X2);
      #pragma unroll
      for (int r = 0; r < 16; ++r) Xs[r] = X2[r];
      st_T(S12, j, ho4, Xs);
      Frag A22; mkfrag_col(S22, j, hoff, A22);
      f32x16 X3 = mmacc(A22, B22, zero16());
      #pragma unroll
      for (int r = 0; r < 16; ++r) Xs[r] = X3[r];
      st_T(S22, j, ho4, Xs);
    }
    __syncthreads();
    // ---------- squaring 1: R11, R12 only (R22 not needed afterwards) --------
    {
      Frag Ac, Br;
      float Xs[16];
      mkfrag_col(S11, j, hoff, Ac);
      mkfrag_row(S11, j, hoff, Br);
      f32x16 X1 = mmacc(Ac, Br, zero16());
      Frag B12; mkfrag_row(S12, j, hoff, B12);
      f32x16 X2 = mmacc(Ac, B12, zero16());
      Frag A12; mkfrag_col(S12, j, hoff, A12);
      Frag B22; mkfrag_row(S22, j, hoff, B22);
      X2 = mmacc(A12, B22, X2);
      #pragma unroll
      for (int r = 0; r < 16; ++r) Xs[r] = X1[r];
      st_T(S11, j, ho4, Xs);
      #pragma unroll
      for (int r = 0; r < 16; ++r) Xs[r] = X2[r];
      st_T(S12, j, ho4, Xs);
    }
    __syncthreads();

    // ---------- Qd = 0.5*(Phi@E12 + (Phi@E12)^T) -> S22 ----------------------
    Frag PhiF;                                  // A-frag AND B-frag of Phi
    mkfrag_col(S11, j, hoff, PhiF);
    {
      Frag B12; mkfrag_row(S12, j, hoff, B12);
      f32x16 Xq = mmacc(PhiF, B12, zero16());
      float Xs[16];
      #pragma unroll
      for (int r = 0; r < 16; ++r) Xs[r] = Xq[r];
      st_T(S22, j, ho4, Xs);                    // buffer[p][q] = QA[q][p]
      __syncthreads();
      float sym[16];
      #pragma unroll
      for (int r = 0; r < 16; ++r) {
        const int row = (r&3) + 8*(r>>2) + ho4;
        const float tv = S22[row*32 + (j ^ XRS(row))];  // QA[j][row]
        sym[r] = 0.5f * (Xs[r] + tv);
      }
      __syncthreads();
      st_T(S22, j, ho4, sym);                   // Qd (symmetric)
    }
    __syncthreads();

    // ---------- 8 propagation steps: cov <- Phi cov Phi^T + Qd ; z <- Phi z ---
    for (int tt = 0; tt < 8; ++tt) {
      Frag Bcov; mkfrag_row(SCV, j, hoff, Bcov);     // Q = cov (symmetric)
      f32x16 G = mmacc(PhiF, Bcov, zero16());        // Phi@cov
      float Gs[16];
      #pragma unroll
      for (int r = 0; r < 16; ++r) Gs[r] = G[r];
      st_T(SA, j, ho4, Gs);                          // SA = G^T
      Frag AG; mkfrag_col(SA, j, hoff, AG);          // A-frag of G
      f32x16 C = mmacc(AG, PhiF, zero16());          // G@Phi^T
      float qdv[16], Cs[16];
      ld16_T(S22, j, ho4, qdv);
      #pragma unroll
      for (int r = 0; r < 16; ++r) Cs[r] = C[r] + qdv[r];
      // z' = Phi@z : lane (j,hh) does half the dot for row j
      float zp = 0.f;
      #pragma unroll
      for (int e = 0; e < 16; ++e) {
        const int kr = 16*hh + e;
        zp += S11[kr*32 + (j ^ XRS(kr))] * zarr[kr]; // Phi[j][kr]
      }
      zp += __shfl_xor(zp, 32);
      st_T(SCV, j, ho4, Cs);                         // cov (symmetric to rounding)
      float* cb = covout + (size_t)(s*8 + tt)*1024;
      #pragma unroll
      for (int r = 0; r < 16; ++r)
        cb[((r&3) + 8*(r>>2) + ho4)*32 + j] = Cs[r];
      if (t < 32) {
        zarr[t] = zp;
        stout[(s*8 + tt)*32 + t] = zp;
      }
      __syncthreads();
    }
  }
}

// ---------------- launch ----------------
extern "C" void kernel_launch(void* const* d_in, const int* in_sizes, int n_in,
                              void* d_out, int out_size, void* d_ws, size_t ws_size,
                              hipStream_t stream) {
  const float* ctx  = (const float*)d_in[0];
  const float* z0   = (const float*)d_in[1];
  const float* S_W  = (const float*)d_in[2];
  const float* S_b  = (const float*)d_in[3];
  const float* L_W  = (const float*)d_in[4];
  const float* L_b  = (const float*)d_in[5];
  const float* G_W  = (const float*)d_in[6];
  const float* G_b  = (const float*)d_in[7];
  const float* Sg_W = (const float*)d_in[8];
  const float* Sg_b = (const float*)d_in[9];
  float* out = (float*)d_out;
  float* ws  = (float*)d_ws;

  float* w_   = ws;                 // [3][4096][8]
  float* q2   = ws + 98304;         // [3][4096][32]
  float* ctxT = ws + 491520;        // [128][4096]
  float* sbsk = ws + 1015808;       // [3][8][1024]
  float* v2   = ws + 1040384;       // [3][1024][1024]
  float* as_  = ws + 4186112;       // [3][4096][1024]
  float* lt   = ws + 16769024;      // [4096][2048] (per-seg reuse)

  kA  <<<dim3(4096, 3), 64,  0, stream>>>(ctx, G_W, G_b, Sg_W, Sg_b, w_, q2);
  kA2 <<<dim3(128, 4),  256, 0, stream>>>(ctx, ctxT);
  kB0 <<<dim3(1024, 3), 256, 0, stream>>>(S_W, v2);
  kB0b<<<dim3(8, 3),    256, 0, stream>>>(S_b, sbsk);
  kB2 <<<dim3(8, 32, 3),256, 0, stream>>>(ctxT, w_, v2, sbsk, as_);
  for (int s = 0; s < 3; ++s) {
    kL  <<<dim3(16, 32), 256, 0, stream>>>(ctxT, L_W, L_b, w_, lt, s);
    kLLT<<<dim3(1024),   128, 0, stream>>>(lt, as_, s);
  }
  kC5 <<<dim3(4096),    64, 0, stream>>>(as_, q2, z0, out);
}

// Round 6
// 706.178 us; speedup vs baseline: 1.9709x; 1.2502x over previous
//
#include <hip/hip_runtime.h>
#include <math.h>

// TVKoopmanMoE: B=4096, C=128, D=32, K=8, R=8, NSEG=3, STEPS=8 each, DT=0.1
//  - kA: gates w (softmax) + diag^2
//  - AS GEMM via MFMA bf16 hi/lo split (kCvtA/kCvtB/kB3):
//      AS = LHS @ V2 + w @ SBsk,  LHS[b][(k,c)] = w[b,k]*ctx[b,c],
//      V2[(k,c)][n] = S_W[c][k,n] - S_W[c][k,nT]  (skew fold),
//      bias folded via K-extension (K=1024 -> 1032, padded 1088).
//      3-product split: Ah@Bh + Ah@Bl + Al@Bh (fp32 acc), err ~1e-4.
//  - sum_k w_k L_k L_k^T = Ltil Ltil^T (kL, kLLT)
//  - kC5: ONE WAVE per b, block-triangular expm via 32x32x16 bf16 MFMA hi/lo.

#define NSEGC 3
#define BSZ   4096
#define MUC   0.14861455999447191f   /* -ln(0.7)/(0.1*24) */
#define XSC   0.025f                 /* DT / 2^SQ = 0.1/4 */
#define XRS(r) (((r) & 7) << 2)

typedef unsigned short ushort_t;
typedef __attribute__((ext_vector_type(8))) short bf16x8;
typedef __attribute__((ext_vector_type(16))) float f32x16;

__device__ __forceinline__ void ld4(float d[4], const float* p) {
  const float4 v = *(const float4*)p; d[0]=v.x; d[1]=v.y; d[2]=v.z; d[3]=v.w;
}
__device__ __forceinline__ void st4(float* p, const float d[4]) {
  *(float4*)p = make_float4(d[0], d[1], d[2], d[3]);
}
__device__ __forceinline__ unsigned short bf_rne(float x) {
  unsigned b = __float_as_uint(x);
  unsigned r = b + 0x7FFFu + ((b >> 16) & 1u);
  return (unsigned short)(r >> 16);
}

// ---------------- kA: gates (softmax(logits/2)) and diag^2 ----------------
__global__ __launch_bounds__(64) void kA(const float* __restrict__ ctx,
    const float* __restrict__ GW, const float* __restrict__ Gb,
    const float* __restrict__ SgW, const float* __restrict__ Sgb,
    float* __restrict__ Wsm, float* __restrict__ Q2) {
  const int b = blockIdx.x, s = blockIdx.y, l = threadIdx.x;
  __shared__ float c[128];
  c[l]      = ctx[(size_t)b*128 + l];
  c[l + 64] = ctx[(size_t)b*128 + 64 + l];
  __syncthreads();
  if (l < 8) {
    float acc = Gb[s*8 + l];
    #pragma unroll 4
    for (int q = 0; q < 128; ++q) acc += c[q] * GW[(size_t)(s*128 + q)*8 + l];
    float li = acc * 0.5f;            // / TEMP (=2)
    float m = li;
    m = fmaxf(m, __shfl_xor(m, 1));
    m = fmaxf(m, __shfl_xor(m, 2));
    m = fmaxf(m, __shfl_xor(m, 4));
    float e = expf(li - m);
    float sum = e;
    sum += __shfl_xor(sum, 1);
    sum += __shfl_xor(sum, 2);
    sum += __shfl_xor(sum, 4);
    Wsm[((size_t)s*BSZ + b)*8 + l] = e / sum;
  } else if (l < 40) {
    const int d = l - 8;
    float acc = Sgb[s*32 + d];
    #pragma unroll 4
    for (int q = 0; q < 128; ++q) acc += c[q] * SgW[(size_t)(s*128 + q)*32 + d];
    float sp = fmaxf(acc, 0.f) + log1pf(expf(-fabsf(acc)));  // stable softplus
    float dg = fminf(sp, 1.0f);
    Q2[((size_t)s*BSZ + b)*32 + d] = dg * dg;
  }
}

// ---------------- kA2: ctxT[c][b] = ctx[b][c] (for kL) ----------------
__global__ __launch_bounds__(256) void kA2(const float* __restrict__ ctx,
                                           float* __restrict__ ctxT) {
  __shared__ float tile[32][33];
  const int bb = blockIdx.x * 32, cc = blockIdx.y * 32;
  const int tx = threadIdx.x & 31, ty = threadIdx.x >> 5;
  for (int r = ty; r < 32; r += 8) tile[r][tx] = ctx[(size_t)(bb + r)*128 + cc + tx];
  __syncthreads();
  for (int r = ty; r < 32; r += 8) ctxT[(size_t)(cc + r)*BSZ + bb + tx] = tile[tx][r];
}

// -------- kCvtA: A'[b][kc] hi/lo bf16; kc<1024: w[k]*ctx[c]; 1024..1031: w; pad 0
__global__ __launch_bounds__(256) void kCvtA(const float* __restrict__ ctx,
    const float* __restrict__ Wsm, ushort_t* __restrict__ Ah,
    ushort_t* __restrict__ Al, int s) {
  __shared__ float cs[128];
  __shared__ float wwv[8];
  const int b = blockIdx.x, t = threadIdx.x;
  if (t < 128) cs[t] = ctx[(size_t)b*128 + t];
  else if (t < 136) wwv[t - 128] = Wsm[((size_t)s*BSZ + b)*8 + (t - 128)];
  __syncthreads();
  for (int kc = t; kc < 1088; kc += 256) {
    float v = 0.f;
    if (kc < 1024) v = wwv[kc >> 7] * cs[kc & 127];
    else if (kc < 1032) v = wwv[kc - 1024];
    const unsigned short h = bf_rne(v);
    const float hf = __uint_as_float(((unsigned)h) << 16);
    Ah[(size_t)b*1088 + kc] = h;
    Al[(size_t)b*1088 + kc] = bf_rne(v - hf);
  }
}

// -------- kCvtB: B'[n][kc] = V2^T hi/lo bf16; rows n, cols kc; bias rows appended
__global__ __launch_bounds__(256) void kCvtB(const float* __restrict__ SW,
    const float* __restrict__ Sb, ushort_t* __restrict__ Bh,
    ushort_t* __restrict__ Bl, int s) {
  const int n = blockIdx.x, t = threadIdx.x;
  const int i = n >> 5, j = n & 31, nT = j*32 + i;
  for (int kc = t; kc < 1088; kc += 256) {
    float v = 0.f;
    if (kc < 1024) {
      const int k = kc >> 7, c = kc & 127;
      const float* base = SW + ((size_t)(s*128 + c))*8192 + (size_t)k*1024;
      v = base[n] - base[nT];
    } else if (kc < 1032) {
      const int k = kc - 1024;
      const float* base = Sb + (size_t)s*8192 + (size_t)k*1024;
      v = base[n] - base[nT];
    }
    const unsigned short h = bf_rne(v);
    const float hf = __uint_as_float(((unsigned)h) << 16);
    Bh[(size_t)n*1088 + kc] = h;
    Bl[(size_t)n*1088 + kc] = bf_rne(v - hf);
  }
}

// -------- kB3: AS_seg = A' @ B'^T via 32x32x16 bf16 MFMA, 3-product hi/lo ----
// Tile 128x128, 4 waves (each 64x64 = 2x2 of 32x32), K-step 64, dbuf LDS,
// global_load_lds(16B) staging with pre-swizzled source (slot ^= row&7).
__global__ __launch_bounds__(256) void kB3(const ushort_t* __restrict__ Ah,
    const ushort_t* __restrict__ Al, const ushort_t* __restrict__ Bh,
    const ushort_t* __restrict__ Bl, float* __restrict__ ASseg) {
  __shared__ ushort_t sArr[2][2][8192];   // [buf][A/B][128 rows x 64 cols]
  const int t = threadIdx.x;
  const int l = t & 63, w = t >> 6;
  const int hh = l >> 5, lane31 = l & 31;
  const int nb = blockIdx.x * 128, bb = blockIdx.y * 128;
  const int wr0 = (w & 1) * 64, wc0 = (w >> 1) * 64;

  const ushort_t* APT[3] = {Ah, Ah, Al};
  const ushort_t* BPT[3] = {Bh, Bl, Bh};

  f32x16 acc[2][2];
  #pragma unroll
  for (int a = 0; a < 2; ++a)
    #pragma unroll
    for (int bq = 0; bq < 2; ++bq)
      #pragma unroll
      for (int e = 0; e < 16; ++e) acc[a][bq][e] = 0.f;

  const int gr = (t >> 3);          // staging row for iter i: gr + i*32? no: gidx=i*256+t
  (void)gr;

  #define STAGE(buf, it) do {                                                  \
    const int p_ = (it) / 17, ks_ = (it) - p_*17;                              \
    const ushort_t* As_ = APT[p_];                                             \
    const ushort_t* Bs_ = BPT[p_];                                             \
    _Pragma("unroll")                                                          \
    for (int i_ = 0; i_ < 4; ++i_) {                                           \
      const int gidx_ = i_*256 + t;                                            \
      const int r_ = gidx_ >> 3, g_ = gidx_ & 7;                               \
      const int gs_ = g_ ^ (r_ & 7);                                           \
      const ushort_t* srcA_ = As_ + (size_t)(bb + r_)*1088 + ks_*64 + gs_*8;   \
      const ushort_t* srcB_ = Bs_ + (size_t)(nb + r_)*1088 + ks_*64 + gs_*8;   \
      __builtin_amdgcn_global_load_lds(                                        \
        (const __attribute__((address_space(1))) unsigned int*)srcA_,          \
        (__attribute__((address_space(3))) unsigned int*)&sArr[buf][0][(i_*256 + w*64)*8], \
        16, 0, 0);                                                             \
      __builtin_amdgcn_global_load_lds(                                        \
        (const __attribute__((address_space(1))) unsigned int*)srcB_,          \
        (__attribute__((address_space(3))) unsigned int*)&sArr[buf][1][(i_*256 + w*64)*8], \
        16, 0, 0);                                                             \
    }                                                                          \
  } while (0)

  STAGE(0, 0);
  int cur = 0;
  #pragma unroll 1
  for (int it = 0; it < 51; ++it) {
    __syncthreads();                      // drain loads into buf[cur]
    if (it + 1 < 51) STAGE(cur ^ 1, it + 1);
    const ushort_t* lA = &sArr[cur][0][0];
    const ushort_t* lB = &sArr[cur][1][0];
    #pragma unroll
    for (int kc = 0; kc < 4; ++kc) {
      bf16x8 af[2], bfr[2];
      #pragma unroll
      for (int rt = 0; rt < 2; ++rt) {
        const int row = wr0 + rt*32 + lane31;
        const int slot = (kc*2 + hh) ^ (row & 7);
        af[rt] = *(const bf16x8*)&lA[row*64 + slot*8];
      }
      #pragma unroll
      for (int ct = 0; ct < 2; ++ct) {
        const int row = wc0 + ct*32 + lane31;
        const int slot = (kc*2 + hh) ^ (row & 7);
        bfr[ct] = *(const bf16x8*)&lB[row*64 + slot*8];
      }
      #pragma unroll
      for (int rt = 0; rt < 2; ++rt)
        #pragma unroll
        for (int ct = 0; ct < 2; ++ct)
          acc[rt][ct] = __builtin_amdgcn_mfma_f32_32x32x16_bf16(
              af[rt], bfr[ct], acc[rt][ct], 0, 0, 0);
    }
    cur ^= 1;
  }
  #undef STAGE

  // epilogue: C/D col=lane&31, row=(reg&3)+8*(reg>>2)+4*(lane>>5)
  #pragma unroll
  for (int rt = 0; rt < 2; ++rt)
    #pragma unroll
    for (int ct = 0; ct < 2; ++ct) {
      float* o = ASseg + ((size_t)(bb + wr0 + rt*32))*1024 + nb + wc0 + ct*32 + lane31;
      #pragma unroll
      for (int reg = 0; reg < 16; ++reg) {
        const int row = (reg & 3) + 8*(reg >> 2) + 4*hh;
        o[(size_t)row*1024] = acc[rt][ct][reg];
      }
    }
}

// ---------------- kL: Ltil = (ctx@L_W + L_b)*sqrt(w) ----------------
__global__ __launch_bounds__(256) void kL(const float* __restrict__ ctxT,
    const float* __restrict__ LW, const float* __restrict__ Lb,
    const float* __restrict__ Wsm, float* __restrict__ LT, int s) {
  __shared__ float At[32][128];
  __shared__ float Bt[32][128];
  __shared__ float wsq[8][128];
  const int t = threadIdx.x;
  const int nb = blockIdx.x * 128, bb = blockIdx.y * 128;
  for (int i = t; i < 1024; i += 256) {
    const int k = i >> 7, x = i & 127;
    wsq[k][x] = sqrtf(Wsm[((size_t)s*BSZ + bb + x)*8 + k]);
  }
  float acc[8][8] = {};
  const int b0 = (t >> 4) * 8, n0 = (t & 15) * 8;
  const int qrow = t >> 3, x0 = (t & 7) * 16;
  for (int c0 = 0; c0 < 128; c0 += 32) {
    __syncthreads();
    #pragma unroll
    for (int rep = 0; rep < 4; ++rep) {
      const int x = x0 + rep*4;
      *(float4*)&At[qrow][x] = *(const float4*)&ctxT[(size_t)(c0 + qrow)*BSZ + bb + x];
      *(float4*)&Bt[qrow][x] =
        *(const float4*)&LW[((size_t)(s*128 + c0 + qrow))*2048 + nb + x];
    }
    __syncthreads();
    #pragma unroll 8
    for (int q = 0; q < 32; ++q) {
      float av[8], bv[8];
      ld4(av, &At[q][b0]); ld4(av + 4, &At[q][b0 + 4]);
      ld4(bv, &Bt[q][n0]); ld4(bv + 4, &Bt[q][n0 + 4]);
      #pragma unroll
      for (int i = 0; i < 8; ++i)
        #pragma unroll
        for (int j = 0; j < 8; ++j) acc[i][j] += av[i] * bv[j];
    }
  }
  const int kidx = (nb + n0) >> 8;
  const int dcol = ((nb + n0) >> 3) & 31;
  float lbv[8];
  #pragma unroll
  for (int j = 0; j < 8; ++j) lbv[j] = Lb[(size_t)s*2048 + nb + n0 + j];
  for (int i = 0; i < 8; ++i) {
    const float wv = wsq[kidx][b0 + i];
    float* dst = LT + (size_t)(bb + b0 + i)*2048 + kidx*256 + dcol;
    #pragma unroll
    for (int j = 0; j < 8; ++j) dst[j*32] = (acc[i][j] + lbv[j]) * wv;
  }
}

// ---------------- kLLT: AS -= Ltil Ltil^T  (4 b per block) ----------------
__global__ __launch_bounds__(128) void kLLT(const float* __restrict__ LT,
                                            float* __restrict__ AS, int s) {
  __shared__ float L4[4][64][32];
  const int t = threadIdx.x;
  const int bbase = blockIdx.x * 4;
  {
    float* l4f = &L4[0][0][0];
    const float* src = LT + (size_t)bbase * 2048;
    for (int i = t*4; i < 8192; i += 512)
      *(float4*)&l4f[i] = *(const float4*)&src[i];
  }
  __syncthreads();
  const int b = t >> 5, u = t & 31;
  const int i0 = (u >> 2) * 4, j0 = (u & 3) * 8;
  float acc[4][8] = {};
  #pragma unroll 8
  for (int kr = 0; kr < 64; ++kr) {
    float pa[4], pb[8];
    ld4(pa, &L4[b][kr][i0]);
    ld4(pb, &L4[b][kr][j0]); ld4(pb + 4, &L4[b][kr][j0 + 4]);
    #pragma unroll
    for (int ii = 0; ii < 4; ++ii)
      #pragma unroll
      for (int jj = 0; jj < 8; ++jj) acc[ii][jj] += pa[ii] * pb[jj];
  }
  float* dst = AS + ((size_t)s*BSZ + bbase + b)*1024;
  for (int ii = 0; ii < 4; ++ii) {
    float x[8];
    ld4(x, &dst[(i0+ii)*32 + j0]); ld4(x + 4, &dst[(i0+ii)*32 + j0 + 4]);
    #pragma unroll
    for (int jj = 0; jj < 8; ++jj) x[jj] -= acc[ii][jj];
    st4(&dst[(i0+ii)*32 + j0], x); st4(&dst[(i0+ii)*32 + j0 + 4], &x[4]);
  }
}

// ================= kC5: MFMA hi/lo expm + propagation, one wave per b =========
struct Frag { bf16x8 h0, l0, h1, l1; };

__device__ __forceinline__ void cvt8(const float x[8], bf16x8& hi, bf16x8& lo) {
  #pragma unroll
  for (int e = 0; e < 8; ++e) {
    unsigned short h = bf_rne(x[e]);
    float hf = __uint_as_float(((unsigned)h) << 16);
    float l = x[e] - hf;                 // exact
    hi[e] = (short)h;
    lo[e] = (short)bf_rne(l);
  }
}
__device__ __forceinline__ void rd_row8(const float* M, int r, int kb, float o[8]) {
  const float* p = M + r*32;
  ld4(o,     p + ((kb)     ^ XRS(r)));
  ld4(o + 4, p + ((kb + 4) ^ XRS(r)));
}
__device__ __forceinline__ void rd_col8(const float* M, int c, int kb, float o[8]) {
  #pragma unroll
  for (int e = 0; e < 8; ++e) o[e] = M[(kb + e)*32 + (c ^ XRS(kb + e))];
}
__device__ __forceinline__ void mkfrag_row(const float* M, int r, int hoff, Frag& f) {
  float t0[8], t1[8];
  rd_row8(M, r, hoff, t0);
  rd_row8(M, r, 16 + hoff, t1);
  cvt8(t0, f.h0, f.l0);
  cvt8(t1, f.h1, f.l1);
}
__device__ __forceinline__ void mkfrag_col(const float* M, int c, int hoff, Frag& f) {
  float t0[8], t1[8];
  rd_col8(M, c, hoff, t0);
  rd_col8(M, c, 16 + hoff, t1);
  cvt8(t0, f.h0, f.l0);
  cvt8(t1, f.h1, f.l1);
}
__device__ __forceinline__ f32x16 mmacc(const Frag& A, const Frag& B, f32x16 acc) {
  acc = __builtin_amdgcn_mfma_f32_32x32x16_bf16(A.h0, B.h0, acc, 0, 0, 0);
  acc = __builtin_amdgcn_mfma_f32_32x32x16_bf16(A.h0, B.l0, acc, 0, 0, 0);
  acc = __builtin_amdgcn_mfma_f32_32x32x16_bf16(A.l0, B.h0, acc, 0, 0, 0);
  acc = __builtin_amdgcn_mfma_f32_32x32x16_bf16(A.h1, B.h1, acc, 0, 0, 0);
  acc = __builtin_amdgcn_mfma_f32_32x32x16_bf16(A.h1, B.l1, acc, 0, 0, 0);
  acc = __builtin_amdgcn_mfma_f32_32x32x16_bf16(A.l1, B.h1, acc, 0, 0, 0);
  return acc;
}
__device__ __forceinline__ f32x16 zero16() {
  f32x16 z = {0.f,0.f,0.f,0.f,0.f,0.f,0.f,0.f,0.f,0.f,0.f,0.f,0.f,0.f,0.f,0.f};
  return z;
}
__device__ __forceinline__ void st_T(float* M, int j, int ho4, const float v[16]) {
  float* p = M + j*32;
  #pragma unroll
  for (int m = 0; m < 4; ++m) st4(p + ((8*m + ho4) ^ XRS(j)), v + 4*m);
}
__device__ __forceinline__ void ld16_T(const float* M, int j, int ho4, float o[16]) {
  const float* p = M + j*32;
  #pragma unroll
  for (int m = 0; m < 4; ++m) ld4(o + 4*m, p + ((8*m + ho4) ^ XRS(j)));
}

__global__ __launch_bounds__(64) void kC5(const float* __restrict__ AS,
    const float* __restrict__ Q2, const float* __restrict__ z0,
    float* __restrict__ out) {
  __shared__ float SA[1024];   // a ; later G scratch
  __shared__ float S11[1024];  // R11^T (Phi^T after squaring)
  __shared__ float S12[1024];  // R12^T (E12^T)
  __shared__ float S22[1024];  // R22^T ; later Qd
  __shared__ float SCV[1024];  // cov (symmetric)
  __shared__ float zarr[32], qds[32];
  const int b = blockIdx.x, t = threadIdx.x;
  const int j = t & 31, hh = t >> 5;
  const int hoff = hh * 8, ho4 = hh * 4;

  if (t < 32) zarr[t] = z0[(size_t)b*32 + t];
  for (int i = t; i < 1024; i += 64) SCV[i] = 0.f;
  __syncthreads();

  float* covout = out + 3145728 + (size_t)b*24576;
  float* stout  = out + (size_t)b*768;

  for (int s = 0; s < NSEGC; ++s) {
    if (t < 32) qds[t] = Q2[((size_t)s*BSZ + b)*32 + t] * XSC;
    const float* asb = AS + ((size_t)s*BSZ + b)*1024;
    float av[16];
    #pragma unroll
    for (int m = 0; m < 4; ++m) ld4(av + 4*m, &asb[j*32 + 16*hh + 4*m]);
    #pragma unroll
    for (int i = 0; i < 16; ++i) if (16*hh + i == j) av[i] -= MUC;
    float ssq = 0.f;
    #pragma unroll
    for (int i = 0; i < 16; ++i) ssq += av[i]*av[i];
    #pragma unroll
    for (int off = 1; off < 64; off <<= 1) ssq += __shfl_xor(ssq, off);
    const float frob = sqrtf(ssq);
    const float sc = (frob > 3.0f ? 3.0f / (frob + 1e-6f) : 1.0f) * XSC;
    #pragma unroll
    for (int i = 0; i < 16; ++i) av[i] *= sc;
    #pragma unroll
    for (int m = 0; m < 4; ++m) {
      st4(&SA[j*32 + ((16*hh + 4*m) ^ XRS(j))], av + 4*m);
      float id[4], zo[4] = {0.f, 0.f, 0.f, 0.f};
      #pragma unroll
      for (int e = 0; e < 4; ++e) id[e] = (16*hh + 4*m + e == j) ? 1.f : 0.f;
      st4(&S11[j*32 + ((16*hh + 4*m) ^ XRS(j))], id);
      st4(&S22[j*32 + ((16*hh + 4*m) ^ XRS(j))], id);
      st4(&S12[j*32 + ((16*hh + 4*m) ^ XRS(j))], zo);
    }
    __syncthreads();
    float qv[16];
    #pragma unroll
    for (int r = 0; r < 16; ++r) qv[r] = qds[(r&3) + 8*(r>>2) + ho4];
    Frag aA, aT;
    mkfrag_row(SA, j, hoff, aA);   // A-frag of a
    mkfrag_col(SA, j, hoff, aT);   // A-frag of a^T

    for (int k = 5; k >= 1; --k) {
      const float rk = 1.0f / (float)k;
      Frag Bf;
      float Xs[16];
      mkfrag_row(S11, j, hoff, Bf);
      f32x16 X = mmacc(aA, Bf, zero16());
      #pragma unroll
      for (int r = 0; r < 16; ++r) {
        const int row = (r&3) + 8*(r>>2) + ho4;
        Xs[r] = X[r]*rk + (row == j ? 1.f : 0.f);
      }
      st_T(S11, j, ho4, Xs);
      mkfrag_row(S12, j, hoff, Bf);
      X = mmacc(aA, Bf, zero16());
      float rv[16];
      ld16_T(S22, j, ho4, rv);
      #pragma unroll
      for (int r = 0; r < 16; ++r) Xs[r] = (X[r] + qv[r]*rv[r]) * rk;
      st_T(S12, j, ho4, Xs);
      mkfrag_row(S22, j, hoff, Bf);
      X = mmacc(aT, Bf, zero16());
      #pragma unroll
      for (int r = 0; r < 16; ++r) {
        const int row = (r&3) + 8*(r>>2) + ho4;
        Xs[r] = (row == j ? 1.f : 0.f) - X[r]*rk;
      }
      st_T(S22, j, ho4, Xs);
    }
    __syncthreads();

    {
      Frag Ac, Br;
      float Xs[16];
      mkfrag_col(S11, j, hoff, Ac);
      mkfrag_row(S11, j, hoff, Br);
      f32x16 X1 = mmacc(Ac, Br, zero16());
      #pragma unroll
      for (int r = 0; r < 16; ++r) Xs[r] = X1[r];
      st_T(S11, j, ho4, Xs);
      Frag B12; mkfrag_row(S12, j, hoff, B12);
      f32x16 X2 = mmacc(Ac, B12, zero16());
      Frag A12; mkfrag_col(S12, j, hoff, A12);
      Frag B22; mkfrag_row(S22, j, hoff, B22);
      X2 = mmacc(A12, B22, X2);
      #pragma unroll
      for (int r = 0; r < 16; ++r) Xs[r] = X2[r];
      st_T(S12, j, ho4, Xs);
      Frag A22; mkfrag_col(S22, j, hoff, A22);
      f32x16 X3 = mmacc(A22, B22, zero16());
      #pragma unroll
      for (int r = 0; r < 16; ++r) Xs[r] = X3[r];
      st_T(S22, j, ho4, Xs);
    }
    __syncthreads();
    {
      Frag Ac, Br;
      float Xs[16];
      mkfrag_col(S11, j, hoff, Ac);
      mkfrag_row(S11, j, hoff, Br);
      f32x16 X1 = mmacc(Ac, Br, zero16());
      Frag B12; mkfrag_row(S12, j, hoff, B12);
      f32x16 X2 = mmacc(Ac, B12, zero16());
      Frag A12; mkfrag_col(S12, j, hoff, A12);
      Frag B22; mkfrag_row(S22, j, hoff, B22);
      X2 = mmacc(A12, B22, X2);
      #pragma unroll
      for (int r = 0; r < 16; ++r) Xs[r] = X1[r];
      st_T(S11, j, ho4, Xs);
      #pragma unroll
      for (int r = 0; r < 16; ++r) Xs[r] = X2[r];
      st_T(S12, j, ho4, Xs);
    }
    __syncthreads();

    Frag PhiF;
    mkfrag_col(S11, j, hoff, PhiF);
    {
      Frag B12; mkfrag_row(S12, j, hoff, B12);
      f32x16 Xq = mmacc(PhiF, B12, zero16());
      float Xs[16];
      #pragma unroll
      for (int r = 0; r < 16; ++r) Xs[r] = Xq[r];
      st_T(S22, j, ho4, Xs);
      __syncthreads();
      float sym[16];
      #pragma unroll
      for (int r = 0; r < 16; ++r) {
        const int row = (r&3) + 8*(r>>2) + ho4;
        const float tv = S22[row*32 + (j ^ XRS(row))];
        sym[r] = 0.5f * (Xs[r] + tv);
      }
      __syncthreads();
      st_T(S22, j, ho4, sym);
    }
    __syncthreads();

    for (int tt = 0; tt < 8; ++tt) {
      Frag Bcov; mkfrag_row(SCV, j, hoff, Bcov);
      f32x16 G = mmacc(PhiF, Bcov, zero16());
      float Gs[16];
      #pragma unroll
      for (int r = 0; r < 16; ++r) Gs[r] = G[r];
      st_T(SA, j, ho4, Gs);
      Frag AG; mkfrag_col(SA, j, hoff, AG);
      f32x16 C = mmacc(AG, PhiF, zero16());
      float qdv[16], Cs[16];
      ld16_T(S22, j, ho4, qdv);
      #pragma unroll
      for (int r = 0; r < 16; ++r) Cs[r] = C[r] + qdv[r];
      float zp = 0.f;
      #pragma unroll
      for (int e = 0; e < 16; ++e) {
        const int kr = 16*hh + e;
        zp += S11[kr*32 + (j ^ XRS(kr))] * zarr[kr];
      }
      zp += __shfl_xor(zp, 32);
      st_T(SCV, j, ho4, Cs);
      float* cb = covout + (size_t)(s*8 + tt)*1024;
      #pragma unroll
      for (int r = 0; r < 16; ++r)
        cb[((r&3) + 8*(r>>2) + ho4)*32 + j] = Cs[r];
      if (t < 32) {
        zarr[t] = zp;
        stout[(s*8 + tt)*32 + t] = zp;
      }
      __syncthreads();
    }
  }
}

// ---------------- launch ----------------
extern "C" void kernel_launch(void* const* d_in, const int* in_sizes, int n_in,
                              void* d_out, int out_size, void* d_ws, size_t ws_size,
                              hipStream_t stream) {
  const float* ctx  = (const float*)d_in[0];
  const float* z0   = (const float*)d_in[1];
  const float* S_W  = (const float*)d_in[2];
  const float* S_b  = (const float*)d_in[3];
  const float* L_W  = (const float*)d_in[4];
  const float* L_b  = (const float*)d_in[5];
  const float* G_W  = (const float*)d_in[6];
  const float* G_b  = (const float*)d_in[7];
  const float* Sg_W = (const float*)d_in[8];
  const float* Sg_b = (const float*)d_in[9];
  float* out = (float*)d_out;
  float* ws  = (float*)d_ws;

  // ws layout (f32 offsets):
  //   w_   0        (98304)     q2 98304 (393216)   ctxT 491520 (524288)
  //   as_  1015808  (12582912)  -> ends 13598720  (54.4 MB)
  //   panels (ushort, per-seg, from f32 13598720):
  //     Ah 4456448u, Al 4456448u, Bh 1114112u, Bl 1114112u  (22.3 MB)
  //   lt (f32 13598720, 8388608) ALIASES panels -- used only after kB3 done.
  float* w_   = ws;
  float* q2   = ws + 98304;
  float* ctxT = ws + 491520;
  float* as_  = ws + 1015808;
  ushort_t* panAh = (ushort_t*)(ws + 13598720);
  ushort_t* panAl = panAh + 4456448;
  ushort_t* panBh = panAl + 4456448;
  ushort_t* panBl = panBh + 1114112;
  float* lt = ws + 13598720;

  kA  <<<dim3(4096, 3), 64,  0, stream>>>(ctx, G_W, G_b, Sg_W, Sg_b, w_, q2);
  kA2 <<<dim3(128, 4),  256, 0, stream>>>(ctx, ctxT);
  for (int s = 0; s < 3; ++s) {
    kCvtB<<<dim3(1024), 256, 0, stream>>>(S_W, S_b, panBh, panBl, s);
    kCvtA<<<dim3(4096), 256, 0, stream>>>(ctx, w_, panAh, panAl, s);
    kB3  <<<dim3(8, 32), 256, 0, stream>>>(panAh, panAl, panBh, panBl,
                                           as_ + (size_t)s*4194304);
  }
  for (int s = 0; s < 3; ++s) {
    kL  <<<dim3(16, 32), 256, 0, stream>>>(ctxT, L_W, L_b, w_, lt, s);
    kLLT<<<dim3(1024),   128, 0, stream>>>(lt, as_, s);
  }
  kC5 <<<dim3(4096),    64, 0, stream>>>(as_, q2, z0, out);
}

// Round 8
// 705.077 us; speedup vs baseline: 1.9740x; 1.0016x over previous
//
#include <hip/hip_runtime.h>
#include <math.h>

// TVKoopmanMoE: B=4096, C=128, D=32, K=8, R=8, NSEG=3, STEPS=8 each, DT=0.1
//  - kA: gates w (softmax) + diag^2
//  - AS GEMM via MFMA bf16 hi/lo split (kCvtA/kCvtB/kB3), bias folded via K-ext
//  - sum_k w_k L_k L_k^T = Ltil Ltil^T (kL, kLLT)  [R6 known-good]
//  - kC7: ONE WAVE per b, block-triangular expm via 32x32x16 bf16 MFMA hi/lo.
//    Identical algorithm to R6's kC5; cov state register-parked (covreg) and
//    staged through the dead S12 buffer during propagation -> 4 LDS matrices
//    (16.3 KB, 9 blocks/CU vs 7).

#define NSEGC 3
#define BSZ   4096
#define MUC   0.14861455999447191f   /* -ln(0.7)/(0.1*24) */
#define XSC   0.025f                 /* DT / 2^SQ = 0.1/4 */
#define XRS(r) (((r) & 7) << 2)

typedef unsigned short ushort_t;
typedef __attribute__((ext_vector_type(8))) short bf16x8;
typedef __attribute__((ext_vector_type(16))) float f32x16;

__device__ __forceinline__ void ld4(float d[4], const float* p) {
  const float4 v = *(const float4*)p; d[0]=v.x; d[1]=v.y; d[2]=v.z; d[3]=v.w;
}
__device__ __forceinline__ void st4(float* p, const float d[4]) {
  *(float4*)p = make_float4(d[0], d[1], d[2], d[3]);
}
__device__ __forceinline__ unsigned short bf_rne(float x) {
  unsigned b = __float_as_uint(x);
  unsigned r = b + 0x7FFFu + ((b >> 16) & 1u);
  return (unsigned short)(r >> 16);
}

// ---------------- kA: gates (softmax(logits/2)) and diag^2 ----------------
__global__ __launch_bounds__(64) void kA(const float* __restrict__ ctx,
    const float* __restrict__ GW, const float* __restrict__ Gb,
    const float* __restrict__ SgW, const float* __restrict__ Sgb,
    float* __restrict__ Wsm, float* __restrict__ Q2) {
  const int b = blockIdx.x, s = blockIdx.y, l = threadIdx.x;
  __shared__ float c[128];
  c[l]      = ctx[(size_t)b*128 + l];
  c[l + 64] = ctx[(size_t)b*128 + 64 + l];
  __syncthreads();
  if (l < 8) {
    float acc = Gb[s*8 + l];
    #pragma unroll 4
    for (int q = 0; q < 128; ++q) acc += c[q] * GW[(size_t)(s*128 + q)*8 + l];
    float li = acc * 0.5f;            // / TEMP (=2)
    float m = li;
    m = fmaxf(m, __shfl_xor(m, 1));
    m = fmaxf(m, __shfl_xor(m, 2));
    m = fmaxf(m, __shfl_xor(m, 4));
    float e = expf(li - m);
    float sum = e;
    sum += __shfl_xor(sum, 1);
    sum += __shfl_xor(sum, 2);
    sum += __shfl_xor(sum, 4);
    Wsm[((size_t)s*BSZ + b)*8 + l] = e / sum;
  } else if (l < 40) {
    const int d = l - 8;
    float acc = Sgb[s*32 + d];
    #pragma unroll 4
    for (int q = 0; q < 128; ++q) acc += c[q] * SgW[(size_t)(s*128 + q)*32 + d];
    float sp = fmaxf(acc, 0.f) + log1pf(expf(-fabsf(acc)));  // stable softplus
    float dg = fminf(sp, 1.0f);
    Q2[((size_t)s*BSZ + b)*32 + d] = dg * dg;
  }
}

// ---------------- kA2: ctxT[c][b] = ctx[b][c] (for kL) ----------------
__global__ __launch_bounds__(256) void kA2(const float* __restrict__ ctx,
                                           float* __restrict__ ctxT) {
  __shared__ float tile[32][33];
  const int bb = blockIdx.x * 32, cc = blockIdx.y * 32;
  const int tx = threadIdx.x & 31, ty = threadIdx.x >> 5;
  for (int r = ty; r < 32; r += 8) tile[r][tx] = ctx[(size_t)(bb + r)*128 + cc + tx];
  __syncthreads();
  for (int r = ty; r < 32; r += 8) ctxT[(size_t)(cc + r)*BSZ + bb + tx] = tile[tx][r];
}

// -------- kCvtA: A'[b][kc] hi/lo bf16; kc<1024: w[k]*ctx[c]; 1024..1031: w; pad 0
__global__ __launch_bounds__(256) void kCvtA(const float* __restrict__ ctx,
    const float* __restrict__ Wsm, ushort_t* __restrict__ Ah,
    ushort_t* __restrict__ Al, int s) {
  __shared__ float cs[128];
  __shared__ float wwv[8];
  const int b = blockIdx.x, t = threadIdx.x;
  if (t < 128) cs[t] = ctx[(size_t)b*128 + t];
  else if (t < 136) wwv[t - 128] = Wsm[((size_t)s*BSZ + b)*8 + (t - 128)];
  __syncthreads();
  for (int kc = t; kc < 1088; kc += 256) {
    float v = 0.f;
    if (kc < 1024) v = wwv[kc >> 7] * cs[kc & 127];
    else if (kc < 1032) v = wwv[kc - 1024];
    const unsigned short h = bf_rne(v);
    const float hf = __uint_as_float(((unsigned)h) << 16);
    Ah[(size_t)b*1088 + kc] = h;
    Al[(size_t)b*1088 + kc] = bf_rne(v - hf);
  }
}

// -------- kCvtB: B'[s][n][kc] = V2^T hi/lo bf16 (all 3 segments, one launch) --
__global__ __launch_bounds__(256) void kCvtB(const float* __restrict__ SW,
    const float* __restrict__ Sb, ushort_t* __restrict__ Bh,
    ushort_t* __restrict__ Bl) {
  const int n = blockIdx.x, s = blockIdx.y, t = threadIdx.x;
  const int i = n >> 5, j = n & 31, nT = j*32 + i;
  ushort_t* bh = Bh + (size_t)s*1114112;
  ushort_t* bl = Bl + (size_t)s*1114112;
  for (int kc = t; kc < 1088; kc += 256) {
    float v = 0.f;
    if (kc < 1024) {
      const int k = kc >> 7, c = kc & 127;
      const float* base = SW + ((size_t)(s*128 + c))*8192 + (size_t)k*1024;
      v = base[n] - base[nT];
    } else if (kc < 1032) {
      const int k = kc - 1024;
      const float* base = Sb + (size_t)s*8192 + (size_t)k*1024;
      v = base[n] - base[nT];
    }
    const unsigned short h = bf_rne(v);
    const float hf = __uint_as_float(((unsigned)h) << 16);
    bh[(size_t)n*1088 + kc] = h;
    bl[(size_t)n*1088 + kc] = bf_rne(v - hf);
  }
}

// -------- kB3: AS_seg = A' @ B'^T via 32x32x16 bf16 MFMA, 3-product hi/lo ----
__global__ __launch_bounds__(256) void kB3(const ushort_t* __restrict__ Ah,
    const ushort_t* __restrict__ Al, const ushort_t* __restrict__ Bh,
    const ushort_t* __restrict__ Bl, float* __restrict__ ASseg) {
  __shared__ ushort_t sArr[2][2][8192];   // [buf][A/B][128 rows x 64 cols]
  const int t = threadIdx.x;
  const int l = t & 63, w = t >> 6;
  const int hh = l >> 5, lane31 = l & 31;
  const int nb = blockIdx.x * 128, bb = blockIdx.y * 128;
  const int wr0 = (w & 1) * 64, wc0 = (w >> 1) * 64;

  const ushort_t* APT[3] = {Ah, Ah, Al};
  const ushort_t* BPT[3] = {Bh, Bl, Bh};

  f32x16 acc[2][2];
  #pragma unroll
  for (int a = 0; a < 2; ++a)
    #pragma unroll
    for (int bq = 0; bq < 2; ++bq)
      #pragma unroll
      for (int e = 0; e < 16; ++e) acc[a][bq][e] = 0.f;

  #define STAGE(buf, it) do {                                                  \
    const int p_ = (it) / 17, ks_ = (it) - p_*17;                              \
    const ushort_t* As_ = APT[p_];                                             \
    const ushort_t* Bs_ = BPT[p_];                                             \
    _Pragma("unroll")                                                          \
    for (int i_ = 0; i_ < 4; ++i_) {                                           \
      const int gidx_ = i_*256 + t;                                            \
      const int r_ = gidx_ >> 3, g_ = gidx_ & 7;                               \
      const int gs_ = g_ ^ (r_ & 7);                                           \
      const ushort_t* srcA_ = As_ + (size_t)(bb + r_)*1088 + ks_*64 + gs_*8;   \
      const ushort_t* srcB_ = Bs_ + (size_t)(nb + r_)*1088 + ks_*64 + gs_*8;   \
      __builtin_amdgcn_global_load_lds(                                        \
        (const __attribute__((address_space(1))) unsigned int*)srcA_,          \
        (__attribute__((address_space(3))) unsigned int*)&sArr[buf][0][(i_*256 + w*64)*8], \
        16, 0, 0);                                                             \
      __builtin_amdgcn_global_load_lds(                                        \
        (const __attribute__((address_space(1))) unsigned int*)srcB_,          \
        (__attribute__((address_space(3))) unsigned int*)&sArr[buf][1][(i_*256 + w*64)*8], \
        16, 0, 0);                                                             \
    }                                                                          \
  } while (0)

  STAGE(0, 0);
  int cur = 0;
  #pragma unroll 1
  for (int it = 0; it < 51; ++it) {
    __syncthreads();                      // drain loads into buf[cur]
    if (it + 1 < 51) STAGE(cur ^ 1, it + 1);
    const ushort_t* lA = &sArr[cur][0][0];
    const ushort_t* lB = &sArr[cur][1][0];
    #pragma unroll
    for (int kc = 0; kc < 4; ++kc) {
      bf16x8 af[2], bfr[2];
      #pragma unroll
      for (int rt = 0; rt < 2; ++rt) {
        const int row = wr0 + rt*32 + lane31;
        const int slot = (kc*2 + hh) ^ (row & 7);
        af[rt] = *(const bf16x8*)&lA[row*64 + slot*8];
      }
      #pragma unroll
      for (int ct = 0; ct < 2; ++ct) {
        const int row = wc0 + ct*32 + lane31;
        const int slot = (kc*2 + hh) ^ (row & 7);
        bfr[ct] = *(const bf16x8*)&lB[row*64 + slot*8];
      }
      #pragma unroll
      for (int rt = 0; rt < 2; ++rt)
        #pragma unroll
        for (int ct = 0; ct < 2; ++ct)
          acc[rt][ct] = __builtin_amdgcn_mfma_f32_32x32x16_bf16(
              af[rt], bfr[ct], acc[rt][ct], 0, 0, 0);
    }
    cur ^= 1;
  }
  #undef STAGE

  #pragma unroll
  for (int rt = 0; rt < 2; ++rt)
    #pragma unroll
    for (int ct = 0; ct < 2; ++ct) {
      float* o = ASseg + ((size_t)(bb + wr0 + rt*32))*1024 + nb + wc0 + ct*32 + lane31;
      #pragma unroll
      for (int reg = 0; reg < 16; ++reg) {
        const int row = (reg & 3) + 8*(reg >> 2) + 4*hh;
        o[(size_t)row*1024] = acc[rt][ct][reg];
      }
    }
}

// ---------------- kL: Ltil = (ctx@L_W + L_b)*sqrt(w) ----------------
__global__ __launch_bounds__(256) void kL(const float* __restrict__ ctxT,
    const float* __restrict__ LW, const float* __restrict__ Lb,
    const float* __restrict__ Wsm, float* __restrict__ LT, int s) {
  __shared__ float At[32][128];
  __shared__ float Bt[32][128];
  __shared__ float wsq[8][128];
  const int t = threadIdx.x;
  const int nb = blockIdx.x * 128, bb = blockIdx.y * 128;
  for (int i = t; i < 1024; i += 256) {
    const int k = i >> 7, x = i & 127;
    wsq[k][x] = sqrtf(Wsm[((size_t)s*BSZ + bb + x)*8 + k]);
  }
  float acc[8][8] = {};
  const int b0 = (t >> 4) * 8, n0 = (t & 15) * 8;
  const int qrow = t >> 3, x0 = (t & 7) * 16;
  for (int c0 = 0; c0 < 128; c0 += 32) {
    __syncthreads();
    #pragma unroll
    for (int rep = 0; rep < 4; ++rep) {
      const int x = x0 + rep*4;
      *(float4*)&At[qrow][x] = *(const float4*)&ctxT[(size_t)(c0 + qrow)*BSZ + bb + x];
      *(float4*)&Bt[qrow][x] =
        *(const float4*)&LW[((size_t)(s*128 + c0 + qrow))*2048 + nb + x];
    }
    __syncthreads();
    #pragma unroll 8
    for (int q = 0; q < 32; ++q) {
      float av[8], bv[8];
      ld4(av, &At[q][b0]); ld4(av + 4, &At[q][b0 + 4]);
      ld4(bv, &Bt[q][n0]); ld4(bv + 4, &Bt[q][n0 + 4]);
      #pragma unroll
      for (int i = 0; i < 8; ++i)
        #pragma unroll
        for (int j = 0; j < 8; ++j) acc[i][j] += av[i] * bv[j];
    }
  }
  const int kidx = (nb + n0) >> 8;
  const int dcol = ((nb + n0) >> 3) & 31;
  float lbv[8];
  #pragma unroll
  for (int j = 0; j < 8; ++j) lbv[j] = Lb[(size_t)s*2048 + nb + n0 + j];
  for (int i = 0; i < 8; ++i) {
    const float wv = wsq[kidx][b0 + i];
    float* dst = LT + (size_t)(bb + b0 + i)*2048 + kidx*256 + dcol;
    #pragma unroll
    for (int j = 0; j < 8; ++j) dst[j*32] = (acc[i][j] + lbv[j]) * wv;
  }
}

// ---------------- kLLT: AS -= Ltil Ltil^T  (4 b per block) ----------------
__global__ __launch_bounds__(128) void kLLT(const float* __restrict__ LT,
                                            float* __restrict__ AS, int s) {
  __shared__ float L4[4][64][32];
  const int t = threadIdx.x;
  const int bbase = blockIdx.x * 4;
  {
    float* l4f = &L4[0][0][0];
    const float* src = LT + (size_t)bbase * 2048;
    for (int i = t*4; i < 8192; i += 512)
      *(float4*)&l4f[i] = *(const float4*)&src[i];
  }
  __syncthreads();
  const int b = t >> 5, u = t & 31;
  const int i0 = (u >> 2) * 4, j0 = (u & 3) * 8;
  float acc[4][8] = {};
  #pragma unroll 8
  for (int kr = 0; kr < 64; ++kr) {
    float pa[4], pb[8];
    ld4(pa, &L4[b][kr][i0]);
    ld4(pb, &L4[b][kr][j0]); ld4(pb + 4, &L4[b][kr][j0 + 4]);
    #pragma unroll
    for (int ii = 0; ii < 4; ++ii)
      #pragma unroll
      for (int jj = 0; jj < 8; ++jj) acc[ii][jj] += pa[ii] * pb[jj];
  }
  float* dst = AS + ((size_t)s*BSZ + bbase + b)*1024;
  for (int ii = 0; ii < 4; ++ii) {
    float x[8];
    ld4(x, &dst[(i0+ii)*32 + j0]); ld4(x + 4, &dst[(i0+ii)*32 + j0 + 4]);
    #pragma unroll
    for (int jj = 0; jj < 8; ++jj) x[jj] -= acc[ii][jj];
    st4(&dst[(i0+ii)*32 + j0], x); st4(&dst[(i0+ii)*32 + j0 + 4], &x[4]);
  }
}

// ================= kC7: MFMA hi/lo expm + propagation, one wave per b =========
// Identical algorithm to R6 kC5; cov parked in covreg (C/D order) and staged
// through S12 (dead after Qd) during propagation. 4 LDS matrices.
struct Frag { bf16x8 h0, l0, h1, l1; };

__device__ __forceinline__ void cvt8(const float x[8], bf16x8& hi, bf16x8& lo) {
  #pragma unroll
  for (int e = 0; e < 8; ++e) {
    unsigned short h = bf_rne(x[e]);
    float hf = __uint_as_float(((unsigned)h) << 16);
    float l = x[e] - hf;                 // exact
    hi[e] = (short)h;
    lo[e] = (short)bf_rne(l);
  }
}
__device__ __forceinline__ void rd_row8(const float* M, int r, int kb, float o[8]) {
  const float* p = M + r*32;
  ld4(o,     p + ((kb)     ^ XRS(r)));
  ld4(o + 4, p + ((kb + 4) ^ XRS(r)));
}
__device__ __forceinline__ void rd_col8(const float* M, int c, int kb, float o[8]) {
  #pragma unroll
  for (int e = 0; e < 8; ++e) o[e] = M[(kb + e)*32 + (c ^ XRS(kb + e))];
}
__device__ __forceinline__ void mkfrag_row(const float* M, int r, int hoff, Frag& f) {
  float t0[8], t1[8];
  rd_row8(M, r, hoff, t0);
  rd_row8(M, r, 16 + hoff, t1);
  cvt8(t0, f.h0, f.l0);
  cvt8(t1, f.h1, f.l1);
}
__device__ __forceinline__ void mkfrag_col(const float* M, int c, int hoff, Frag& f) {
  float t0[8], t1[8];
  rd_col8(M, c, hoff, t0);
  rd_col8(M, c, 16 + hoff, t1);
  cvt8(t0, f.h0, f.l0);
  cvt8(t1, f.h1, f.l1);
}
__device__ __forceinline__ f32x16 mmacc(const Frag& A, const Frag& B, f32x16 acc) {
  acc = __builtin_amdgcn_mfma_f32_32x32x16_bf16(A.h0, B.h0, acc, 0, 0, 0);
  acc = __builtin_amdgcn_mfma_f32_32x32x16_bf16(A.h0, B.l0, acc, 0, 0, 0);
  acc = __builtin_amdgcn_mfma_f32_32x32x16_bf16(A.l0, B.h0, acc, 0, 0, 0);
  acc = __builtin_amdgcn_mfma_f32_32x32x16_bf16(A.h1, B.h1, acc, 0, 0, 0);
  acc = __builtin_amdgcn_mfma_f32_32x32x16_bf16(A.h1, B.l1, acc, 0, 0, 0);
  acc = __builtin_amdgcn_mfma_f32_32x32x16_bf16(A.l1, B.h1, acc, 0, 0, 0);
  return acc;
}
__device__ __forceinline__ f32x16 zero16() {
  f32x16 z = {0.f,0.f,0.f,0.f,0.f,0.f,0.f,0.f,0.f,0.f,0.f,0.f,0.f,0.f,0.f,0.f};
  return z;
}
__device__ __forceinline__ void st_T(float* M, int j, int ho4, const float v[16]) {
  float* p = M + j*32;
  #pragma unroll
  for (int m = 0; m < 4; ++m) st4(p + ((8*m + ho4) ^ XRS(j)), v + 4*m);
}
__device__ __forceinline__ void ld16_T(const float* M, int j, int ho4, float o[16]) {
  const float* p = M + j*32;
  #pragma unroll
  for (int m = 0; m < 4; ++m) ld4(o + 4*m, p + ((8*m + ho4) ^ XRS(j)));
}

__global__ __launch_bounds__(64) void kC7(const float* __restrict__ AS,
    const float* __restrict__ Q2, const float* __restrict__ z0,
    float* __restrict__ out) {
  __shared__ float SA[1024];   // a ; later G scratch
  __shared__ float S11[1024];  // R11^T (Phi^T after squaring)
  __shared__ float S12[1024];  // R12^T (E12^T) ; later cov buffer
  __shared__ float S22[1024];  // R22^T ; later Qd
  __shared__ float zarr[32], qds[32];
  const int b = blockIdx.x, t = threadIdx.x;
  const int j = t & 31, hh = t >> 5;
  const int hoff = hh * 8, ho4 = hh * 4;

  if (t < 32) zarr[t] = z0[(size_t)b*32 + t];
  float covreg[16];
  #pragma unroll
  for (int r = 0; r < 16; ++r) covreg[r] = 0.f;
  __syncthreads();

  float* covout = out + 3145728 + (size_t)b*24576;
  float* stout  = out + (size_t)b*768;

  for (int s = 0; s < NSEGC; ++s) {
    // ---------- init: load A, -muI, frob clamp, scale; a, t11=I, t12=0, t22=I --
    if (t < 32) qds[t] = Q2[((size_t)s*BSZ + b)*32 + t] * XSC;
    const float* asb = AS + ((size_t)s*BSZ + b)*1024;
    float av[16];
    #pragma unroll
    for (int m = 0; m < 4; ++m) ld4(av + 4*m, &asb[j*32 + 16*hh + 4*m]);
    #pragma unroll
    for (int i = 0; i < 16; ++i) if (16*hh + i == j) av[i] -= MUC;
    float ssq = 0.f;
    #pragma unroll
    for (int i = 0; i < 16; ++i) ssq += av[i]*av[i];
    #pragma unroll
    for (int off = 1; off < 64; off <<= 1) ssq += __shfl_xor(ssq, off);
    const float frob = sqrtf(ssq);
    const float sc = (frob > 3.0f ? 3.0f / (frob + 1e-6f) : 1.0f) * XSC;
    #pragma unroll
    for (int i = 0; i < 16; ++i) av[i] *= sc;
    #pragma unroll
    for (int m = 0; m < 4; ++m) {
      st4(&SA[j*32 + ((16*hh + 4*m) ^ XRS(j))], av + 4*m);
      float id[4], zo[4] = {0.f, 0.f, 0.f, 0.f};
      #pragma unroll
      for (int e = 0; e < 4; ++e) id[e] = (16*hh + 4*m + e == j) ? 1.f : 0.f;
      st4(&S11[j*32 + ((16*hh + 4*m) ^ XRS(j))], id);
      st4(&S22[j*32 + ((16*hh + 4*m) ^ XRS(j))], id);
      st4(&S12[j*32 + ((16*hh + 4*m) ^ XRS(j))], zo);
    }
    __syncthreads();
    float qv[16];
    #pragma unroll
    for (int r = 0; r < 16; ++r) qv[r] = qds[(r&3) + 8*(r>>2) + ho4];
    Frag aA, aT;
    mkfrag_row(SA, j, hoff, aA);   // A-frag of a
    mkfrag_col(SA, j, hoff, aT);   // A-frag of a^T

    // ---------- Taylor Horner ORDER=5 on X=[[a,q],[0,-a^T]] (transposed blocks)
    for (int k = 5; k >= 1; --k) {
      const float rk = 1.0f / (float)k;
      Frag Bf;
      float Xs[16];
      mkfrag_row(S11, j, hoff, Bf);
      f32x16 X = mmacc(aA, Bf, zero16());
      #pragma unroll
      for (int r = 0; r < 16; ++r) {
        const int row = (r&3) + 8*(r>>2) + ho4;
        Xs[r] = X[r]*rk + (row == j ? 1.f : 0.f);
      }
      st_T(S11, j, ho4, Xs);
      mkfrag_row(S12, j, hoff, Bf);
      X = mmacc(aA, Bf, zero16());
      float rv[16];
      ld16_T(S22, j, ho4, rv);
      #pragma unroll
      for (int r = 0; r < 16; ++r) Xs[r] = (X[r] + qv[r]*rv[r]) * rk;
      st_T(S12, j, ho4, Xs);
      mkfrag_row(S22, j, hoff, Bf);
      X = mmacc(aT, Bf, zero16());
      #pragma unroll
      for (int r = 0; r < 16; ++r) {
        const int row = (r&3) + 8*(r>>2) + ho4;
        Xs[r] = (row == j ? 1.f : 0.f) - X[r]*rk;
      }
      st_T(S22, j, ho4, Xs);
    }
    __syncthreads();

    // ---------- squaring 0: R11<-R11@R11, R12<-R11@R12+R12@R22, R22<-R22@R22 --
    {
      Frag Ac, Br;
      float Xs[16];
      mkfrag_col(S11, j, hoff, Ac);
      mkfrag_row(S11, j, hoff, Br);
      f32x16 X1 = mmacc(Ac, Br, zero16());
      #pragma unroll
      for (int r = 0; r < 16; ++r) Xs[r] = X1[r];
      st_T(S11, j, ho4, Xs);
      Frag B12; mkfrag_row(S12, j, hoff, B12);
      f32x16 X2 = mmacc(Ac, B12, zero16());
      Frag A12; mkfrag_col(S12, j, hoff, A12);
      Frag B22; mkfrag_row(S22, j, hoff, B22);
      X2 = mmacc(A12, B22, X2);
      #pragma unroll
      for (int r = 0; r < 16; ++r) Xs[r] = X2[r];
      st_T(S12, j, ho4, Xs);
      Frag A22; mkfrag_col(S22, j, hoff, A22);
      f32x16 X3 = mmacc(A22, B22, zero16());
      #pragma unroll
      for (int r = 0; r < 16; ++r) Xs[r] = X3[r];
      st_T(S22, j, ho4, Xs);
    }
    __syncthreads();
    // ---------- squaring 1: R11, R12 only (R22 not needed afterwards) --------
    {
      Frag Ac, Br;
      float Xs[16];
      mkfrag_col(S11, j, hoff, Ac);
      mkfrag_row(S11, j, hoff, Br);
      f32x16 X1 = mmacc(Ac, Br, zero16());
      Frag B12; mkfrag_row(S12, j, hoff, B12);
      f32x16 X2 = mmacc(Ac, B12, zero16());
      Frag A12; mkfrag_col(S12, j, hoff, A12);
      Frag B22; mkfrag_row(S22, j, hoff, B22);
      X2 = mmacc(A12, B22, X2);
      #pragma unroll
      for (int r = 0; r < 16; ++r) Xs[r] = X1[r];
      st_T(S11, j, ho4, Xs);
      #pragma unroll
      for (int r = 0; r < 16; ++r) Xs[r] = X2[r];
      st_T(S12, j, ho4, Xs);
    }
    __syncthreads();

    // ---------- Qd = 0.5*(Phi@E12 + (Phi@E12)^T) -> S22 ----------------------
    Frag PhiF;
    mkfrag_col(S11, j, hoff, PhiF);
    {
      Frag B12; mkfrag_row(S12, j, hoff, B12);
      f32x16 Xq = mmacc(PhiF, B12, zero16());
      float Xs[16];
      #pragma unroll
      for (int r = 0; r < 16; ++r) Xs[r] = Xq[r];
      st_T(S22, j, ho4, Xs);
      __syncthreads();
      float sym[16];
      #pragma unroll
      for (int r = 0; r < 16; ++r) {
        const int row = (r&3) + 8*(r>>2) + ho4;
        const float tv = S22[row*32 + (j ^ XRS(row))];
        sym[r] = 0.5f * (Xs[r] + tv);
      }
      __syncthreads();
      st_T(S22, j, ho4, sym);
    }
    __syncthreads();

    // ---------- stage cov (covreg, C/D order) into S12 (E12 dead) ------------
    st_T(S12, j, ho4, covreg);
    __syncthreads();

    // ---------- 8 propagation steps: cov <- Phi cov Phi^T + Qd ; z <- Phi z ---
    for (int tt = 0; tt < 8; ++tt) {
      Frag Bcov; mkfrag_row(S12, j, hoff, Bcov);
      f32x16 G = mmacc(PhiF, Bcov, zero16());
      float Gs[16];
      #pragma unroll
      for (int r = 0; r < 16; ++r) Gs[r] = G[r];
      st_T(SA, j, ho4, Gs);
      Frag AG; mkfrag_col(SA, j, hoff, AG);
      f32x16 C = mmacc(AG, PhiF, zero16());
      float qdv[16], Cs[16];
      ld16_T(S22, j, ho4, qdv);
      #pragma unroll
      for (int r = 0; r < 16; ++r) Cs[r] = C[r] + qdv[r];
      float zp = 0.f;
      #pragma unroll
      for (int e = 0; e < 16; ++e) {
        const int kr = 16*hh + e;
        zp += S11[kr*32 + (j ^ XRS(kr))] * zarr[kr];
      }
      zp += __shfl_xor(zp, 32);
      st_T(S12, j, ho4, Cs);
      #pragma unroll
      for (int r = 0; r < 16; ++r) covreg[r] = Cs[r];
      float* cb = covout + (size_t)(s*8 + tt)*1024;
      #pragma unroll
      for (int r = 0; r < 16; ++r)
        cb[((r&3) + 8*(r>>2) + ho4)*32 + j] = Cs[r];
      if (t < 32) {
        zarr[t] = zp;
        stout[(s*8 + tt)*32 + t] = zp;
      }
      __syncthreads();
    }
  }
}

// ---------------- launch ----------------
extern "C" void kernel_launch(void* const* d_in, const int* in_sizes, int n_in,
                              void* d_out, int out_size, void* d_ws, size_t ws_size,
                              hipStream_t stream) {
  const float* ctx  = (const float*)d_in[0];
  const float* z0   = (const float*)d_in[1];
  const float* S_W  = (const float*)d_in[2];
  const float* S_b  = (const float*)d_in[3];
  const float* L_W  = (const float*)d_in[4];
  const float* L_b  = (const float*)d_in[5];
  const float* G_W  = (const float*)d_in[6];
  const float* G_b  = (const float*)d_in[7];
  const float* Sg_W = (const float*)d_in[8];
  const float* Sg_b = (const float*)d_in[9];
  float* out = (float*)d_out;
  float* ws  = (float*)d_ws;

  // ws layout (f32 offsets):
  //   w_ 0 (98304) | q2 98304 (393216) | ctxT 491520 (524288)
  //   as_ 1015808 (12582912) -> 13598720
  //   phase1: panAh/panAl (8912896u) @13598720, panB3 hi/lo (6684672u) after
  //           -> ends f32 21397504 (85.6 MB)
  //   phase2: lt (fp32 8388608) ALIASES panels @13598720 -> ends 21987328 (88 MB)
  float* w_   = ws;
  float* q2   = ws + 98304;
  float* ctxT = ws + 491520;
  float* as_  = ws + 1015808;
  ushort_t* panAh  = (ushort_t*)(ws + 13598720);
  ushort_t* panAl  = panAh + 4456448;
  ushort_t* panBh3 = panAl + 4456448;
  ushort_t* panBl3 = panBh3 + 3342336;
  float* lt = ws + 13598720;

  kA   <<<dim3(4096, 3), 64,  0, stream>>>(ctx, G_W, G_b, Sg_W, Sg_b, w_, q2);
  kA2  <<<dim3(128, 4),  256, 0, stream>>>(ctx, ctxT);
  kCvtB<<<dim3(1024, 3), 256, 0, stream>>>(S_W, S_b, panBh3, panBl3);
  for (int s = 0; s < 3; ++s) {
    kCvtA<<<dim3(4096), 256, 0, stream>>>(ctx, w_, panAh, panAl, s);
    kB3  <<<dim3(8, 32), 256, 0, stream>>>(panAh, panAl,
                                           panBh3 + (size_t)s*1114112,
                                           panBl3 + (size_t)s*1114112,
                                           as_ + (size_t)s*4194304);
  }
  for (int s = 0; s < 3; ++s) {
    kL  <<<dim3(16, 32), 256, 0, stream>>>(ctxT, L_W, L_b, w_, lt, s);
    kLLT<<<dim3(1024),   128, 0, stream>>>(lt, as_, s);
  }
  kC7 <<<dim3(4096),    64, 0, stream>>>(as_, q2, z0, out);
}

// Round 10
// 630.351 us; speedup vs baseline: 2.2080x; 1.1185x over previous
//
#include <hip/hip_runtime.h>
#include <math.h>

// TVKoopmanMoE: B=4096, C=128, D=32, K=8, R=8, NSEG=3, STEPS=8 each, DT=0.1
//  - kA: gates w (softmax) + diag^2
//  - AS GEMM via MFMA bf16 hi/lo split (kCvtA/kCvtB/kB3), bias folded via K-ext
//  - sum_k w_k L_k L_k^T = Ltil Ltil^T (kL, kLLT)
//  - kC9: ONE WAVE per b, block-triangular expm via 32x32x16 bf16 MFMA hi/lo.
//    R8's kC7 with ONE change: cvt8 uses TRUNCATION split + v_perm_b32 packing
//    (pure builtins -- the R7/R9 inline-asm cvtpk path miscompiles; perm is a
//    tracked intrinsic). ~3 VALU ops/elem vs ~12 for software bf_rne.

#define NSEGC 3
#define BSZ   4096
#define MUC   0.14861455999447191f   /* -ln(0.7)/(0.1*24) */
#define XSC   0.025f                 /* DT / 2^SQ = 0.1/4 */
#define XRS(r) (((r) & 7) << 2)

typedef unsigned short ushort_t;
typedef unsigned int uint_t;
typedef __attribute__((ext_vector_type(8))) short bf16x8;
typedef __attribute__((ext_vector_type(16))) float f32x16;

__device__ __forceinline__ void ld4(float d[4], const float* p) {
  const float4 v = *(const float4*)p; d[0]=v.x; d[1]=v.y; d[2]=v.z; d[3]=v.w;
}
__device__ __forceinline__ void st4(float* p, const float d[4]) {
  *(float4*)p = make_float4(d[0], d[1], d[2], d[3]);
}
__device__ __forceinline__ unsigned short bf_rne(float x) {
  unsigned b = __float_as_uint(x);
  unsigned r = b + 0x7FFFu + ((b >> 16) & 1u);
  return (unsigned short)(r >> 16);
}

// ---------------- kA: gates (softmax(logits/2)) and diag^2 ----------------
__global__ __launch_bounds__(64) void kA(const float* __restrict__ ctx,
    const float* __restrict__ GW, const float* __restrict__ Gb,
    const float* __restrict__ SgW, const float* __restrict__ Sgb,
    float* __restrict__ Wsm, float* __restrict__ Q2) {
  const int b = blockIdx.x, s = blockIdx.y, l = threadIdx.x;
  __shared__ float c[128];
  c[l]      = ctx[(size_t)b*128 + l];
  c[l + 64] = ctx[(size_t)b*128 + 64 + l];
  __syncthreads();
  if (l < 8) {
    float acc = Gb[s*8 + l];
    #pragma unroll 4
    for (int q = 0; q < 128; ++q) acc += c[q] * GW[(size_t)(s*128 + q)*8 + l];
    float li = acc * 0.5f;            // / TEMP (=2)
    float m = li;
    m = fmaxf(m, __shfl_xor(m, 1));
    m = fmaxf(m, __shfl_xor(m, 2));
    m = fmaxf(m, __shfl_xor(m, 4));
    float e = expf(li - m);
    float sum = e;
    sum += __shfl_xor(sum, 1);
    sum += __shfl_xor(sum, 2);
    sum += __shfl_xor(sum, 4);
    Wsm[((size_t)s*BSZ + b)*8 + l] = e / sum;
  } else if (l < 40) {
    const int d = l - 8;
    float acc = Sgb[s*32 + d];
    #pragma unroll 4
    for (int q = 0; q < 128; ++q) acc += c[q] * SgW[(size_t)(s*128 + q)*32 + d];
    float sp = fmaxf(acc, 0.f) + log1pf(expf(-fabsf(acc)));  // stable softplus
    float dg = fminf(sp, 1.0f);
    Q2[((size_t)s*BSZ + b)*32 + d] = dg * dg;
  }
}

// ---------------- kA2: ctxT[c][b] = ctx[b][c] (for kL) ----------------
__global__ __launch_bounds__(256) void kA2(const float* __restrict__ ctx,
                                           float* __restrict__ ctxT) {
  __shared__ float tile[32][33];
  const int bb = blockIdx.x * 32, cc = blockIdx.y * 32;
  const int tx = threadIdx.x & 31, ty = threadIdx.x >> 5;
  for (int r = ty; r < 32; r += 8) tile[r][tx] = ctx[(size_t)(bb + r)*128 + cc + tx];
  __syncthreads();
  for (int r = ty; r < 32; r += 8) ctxT[(size_t)(cc + r)*BSZ + bb + tx] = tile[tx][r];
}

// -------- kCvtA: A'[b][kc] hi/lo bf16; kc<1024: w[k]*ctx[c]; 1024..1031: w; pad 0
__global__ __launch_bounds__(256) void kCvtA(const float* __restrict__ ctx,
    const float* __restrict__ Wsm, ushort_t* __restrict__ Ah,
    ushort_t* __restrict__ Al, int s) {
  __shared__ float cs[128];
  __shared__ float wwv[8];
  const int b = blockIdx.x, t = threadIdx.x;
  if (t < 128) cs[t] = ctx[(size_t)b*128 + t];
  else if (t < 136) wwv[t - 128] = Wsm[((size_t)s*BSZ + b)*8 + (t - 128)];
  __syncthreads();
  for (int kc = t; kc < 1088; kc += 256) {
    float v = 0.f;
    if (kc < 1024) v = wwv[kc >> 7] * cs[kc & 127];
    else if (kc < 1032) v = wwv[kc - 1024];
    const unsigned short h = bf_rne(v);
    const float hf = __uint_as_float(((unsigned)h) << 16);
    Ah[(size_t)b*1088 + kc] = h;
    Al[(size_t)b*1088 + kc] = bf_rne(v - hf);
  }
}

// -------- kCvtB: B'[s][n][kc] = V2^T hi/lo bf16 (all 3 segments, one launch) --
__global__ __launch_bounds__(256) void kCvtB(const float* __restrict__ SW,
    const float* __restrict__ Sb, ushort_t* __restrict__ Bh,
    ushort_t* __restrict__ Bl) {
  const int n = blockIdx.x, s = blockIdx.y, t = threadIdx.x;
  const int i = n >> 5, j = n & 31, nT = j*32 + i;
  ushort_t* bh = Bh + (size_t)s*1114112;
  ushort_t* bl = Bl + (size_t)s*1114112;
  for (int kc = t; kc < 1088; kc += 256) {
    float v = 0.f;
    if (kc < 1024) {
      const int k = kc >> 7, c = kc & 127;
      const float* base = SW + ((size_t)(s*128 + c))*8192 + (size_t)k*1024;
      v = base[n] - base[nT];
    } else if (kc < 1032) {
      const int k = kc - 1024;
      const float* base = Sb + (size_t)s*8192 + (size_t)k*1024;
      v = base[n] - base[nT];
    }
    const unsigned short h = bf_rne(v);
    const float hf = __uint_as_float(((unsigned)h) << 16);
    bh[(size_t)n*1088 + kc] = h;
    bl[(size_t)n*1088 + kc] = bf_rne(v - hf);
  }
}

// -------- kB3: AS_seg = A' @ B'^T via 32x32x16 bf16 MFMA, 3-product hi/lo ----
__global__ __launch_bounds__(256) void kB3(const ushort_t* __restrict__ Ah,
    const ushort_t* __restrict__ Al, const ushort_t* __restrict__ Bh,
    const ushort_t* __restrict__ Bl, float* __restrict__ ASseg) {
  __shared__ ushort_t sArr[2][2][8192];   // [buf][A/B][128 rows x 64 cols]
  const int t = threadIdx.x;
  const int l = t & 63, w = t >> 6;
  const int hh = l >> 5, lane31 = l & 31;
  const int nb = blockIdx.x * 128, bb = blockIdx.y * 128;
  const int wr0 = (w & 1) * 64, wc0 = (w >> 1) * 64;

  const ushort_t* APT[3] = {Ah, Ah, Al};
  const ushort_t* BPT[3] = {Bh, Bl, Bh};

  f32x16 acc[2][2];
  #pragma unroll
  for (int a = 0; a < 2; ++a)
    #pragma unroll
    for (int bq = 0; bq < 2; ++bq)
      #pragma unroll
      for (int e = 0; e < 16; ++e) acc[a][bq][e] = 0.f;

  #define STAGE(buf, it) do {                                                  \
    const int p_ = (it) / 17, ks_ = (it) - p_*17;                              \
    const ushort_t* As_ = APT[p_];                                             \
    const ushort_t* Bs_ = BPT[p_];                                             \
    _Pragma("unroll")                                                          \
    for (int i_ = 0; i_ < 4; ++i_) {                                           \
      const int gidx_ = i_*256 + t;                                            \
      const int r_ = gidx_ >> 3, g_ = gidx_ & 7;                               \
      const int gs_ = g_ ^ (r_ & 7);                                           \
      const ushort_t* srcA_ = As_ + (size_t)(bb + r_)*1088 + ks_*64 + gs_*8;   \
      const ushort_t* srcB_ = Bs_ + (size_t)(nb + r_)*1088 + ks_*64 + gs_*8;   \
      __builtin_amdgcn_global_load_lds(                                        \
        (const __attribute__((address_space(1))) unsigned int*)srcA_,          \
        (__attribute__((address_space(3))) unsigned int*)&sArr[buf][0][(i_*256 + w*64)*8], \
        16, 0, 0);                                                             \
      __builtin_amdgcn_global_load_lds(                                        \
        (const __attribute__((address_space(1))) unsigned int*)srcB_,          \
        (__attribute__((address_space(3))) unsigned int*)&sArr[buf][1][(i_*256 + w*64)*8], \
        16, 0, 0);                                                             \
    }                                                                          \
  } while (0)

  STAGE(0, 0);
  int cur = 0;
  #pragma unroll 1
  for (int it = 0; it < 51; ++it) {
    __syncthreads();                      // drain loads into buf[cur]
    if (it + 1 < 51) STAGE(cur ^ 1, it + 1);
    const ushort_t* lA = &sArr[cur][0][0];
    const ushort_t* lB = &sArr[cur][1][0];
    #pragma unroll
    for (int kc = 0; kc < 4; ++kc) {
      bf16x8 af[2], bfr[2];
      #pragma unroll
      for (int rt = 0; rt < 2; ++rt) {
        const int row = wr0 + rt*32 + lane31;
        const int slot = (kc*2 + hh) ^ (row & 7);
        af[rt] = *(const bf16x8*)&lA[row*64 + slot*8];
      }
      #pragma unroll
      for (int ct = 0; ct < 2; ++ct) {
        const int row = wc0 + ct*32 + lane31;
        const int slot = (kc*2 + hh) ^ (row & 7);
        bfr[ct] = *(const bf16x8*)&lB[row*64 + slot*8];
      }
      #pragma unroll
      for (int rt = 0; rt < 2; ++rt)
        #pragma unroll
        for (int ct = 0; ct < 2; ++ct)
          acc[rt][ct] = __builtin_amdgcn_mfma_f32_32x32x16_bf16(
              af[rt], bfr[ct], acc[rt][ct], 0, 0, 0);
    }
    cur ^= 1;
  }
  #undef STAGE

  #pragma unroll
  for (int rt = 0; rt < 2; ++rt)
    #pragma unroll
    for (int ct = 0; ct < 2; ++ct) {
      float* o = ASseg + ((size_t)(bb + wr0 + rt*32))*1024 + nb + wc0 + ct*32 + lane31;
      #pragma unroll
      for (int reg = 0; reg < 16; ++reg) {
        const int row = (reg & 3) + 8*(reg >> 2) + 4*hh;
        o[(size_t)row*1024] = acc[rt][ct][reg];
      }
    }
}

// ---------------- kL: Ltil = (ctx@L_W + L_b)*sqrt(w) ----------------
__global__ __launch_bounds__(256) void kL(const float* __restrict__ ctxT,
    const float* __restrict__ LW, const float* __restrict__ Lb,
    const float* __restrict__ Wsm, float* __restrict__ LT, int s) {
  __shared__ float At[32][128];
  __shared__ float Bt[32][128];
  __shared__ float wsq[8][128];
  const int t = threadIdx.x;
  const int nb = blockIdx.x * 128, bb = blockIdx.y * 128;
  for (int i = t; i < 1024; i += 256) {
    const int k = i >> 7, x = i & 127;
    wsq[k][x] = sqrtf(Wsm[((size_t)s*BSZ + bb + x)*8 + k]);
  }
  float acc[8][8] = {};
  const int b0 = (t >> 4) * 8, n0 = (t & 15) * 8;
  const int qrow = t >> 3, x0 = (t & 7) * 16;
  for (int c0 = 0; c0 < 128; c0 += 32) {
    __syncthreads();
    #pragma unroll
    for (int rep = 0; rep < 4; ++rep) {
      const int x = x0 + rep*4;
      *(float4*)&At[qrow][x] = *(const float4*)&ctxT[(size_t)(c0 + qrow)*BSZ + bb + x];
      *(float4*)&Bt[qrow][x] =
        *(const float4*)&LW[((size_t)(s*128 + c0 + qrow))*2048 + nb + x];
    }
    __syncthreads();
    #pragma unroll 8
    for (int q = 0; q < 32; ++q) {
      float av[8], bv[8];
      ld4(av, &At[q][b0]); ld4(av + 4, &At[q][b0 + 4]);
      ld4(bv, &Bt[q][n0]); ld4(bv + 4, &Bt[q][n0 + 4]);
      #pragma unroll
      for (int i = 0; i < 8; ++i)
        #pragma unroll
        for (int j = 0; j < 8; ++j) acc[i][j] += av[i] * bv[j];
    }
  }
  const int kidx = (nb + n0) >> 8;
  const int dcol = ((nb + n0) >> 3) & 31;
  float lbv[8];
  #pragma unroll
  for (int j = 0; j < 8; ++j) lbv[j] = Lb[(size_t)s*2048 + nb + n0 + j];
  for (int i = 0; i < 8; ++i) {
    const float wv = wsq[kidx][b0 + i];
    float* dst = LT + (size_t)(bb + b0 + i)*2048 + kidx*256 + dcol;
    #pragma unroll
    for (int j = 0; j < 8; ++j) dst[j*32] = (acc[i][j] + lbv[j]) * wv;
  }
}

// ---------------- kLLT: AS -= Ltil Ltil^T  (4 b per block) ----------------
__global__ __launch_bounds__(128) void kLLT(const float* __restrict__ LT,
                                            float* __restrict__ AS, int s) {
  __shared__ float L4[4][64][32];
  const int t = threadIdx.x;
  const int bbase = blockIdx.x * 4;
  {
    float* l4f = &L4[0][0][0];
    const float* src = LT + (size_t)bbase * 2048;
    for (int i = t*4; i < 8192; i += 512)
      *(float4*)&l4f[i] = *(const float4*)&src[i];
  }
  __syncthreads();
  const int b = t >> 5, u = t & 31;
  const int i0 = (u >> 2) * 4, j0 = (u & 3) * 8;
  float acc[4][8] = {};
  #pragma unroll 8
  for (int kr = 0; kr < 64; ++kr) {
    float pa[4], pb[8];
    ld4(pa, &L4[b][kr][i0]);
    ld4(pb, &L4[b][kr][j0]); ld4(pb + 4, &L4[b][kr][j0 + 4]);
    #pragma unroll
    for (int ii = 0; ii < 4; ++ii)
      #pragma unroll
      for (int jj = 0; jj < 8; ++jj) acc[ii][jj] += pa[ii] * pb[jj];
  }
  float* dst = AS + ((size_t)s*BSZ + bbase + b)*1024;
  for (int ii = 0; ii < 4; ++ii) {
    float x[8];
    ld4(x, &dst[(i0+ii)*32 + j0]); ld4(x + 4, &dst[(i0+ii)*32 + j0 + 4]);
    #pragma unroll
    for (int jj = 0; jj < 8; ++jj) x[jj] -= acc[ii][jj];
    st4(&dst[(i0+ii)*32 + j0], x); st4(&dst[(i0+ii)*32 + j0 + 4], &x[4]);
  }
}

// ================= kC9: MFMA hi/lo expm + propagation, one wave per b =========
// R8's kC7 with cvt8 via truncation split + v_perm_b32 packing (no inline asm).
struct Frag { bf16x8 h0, l0, h1, l1; };

__device__ __forceinline__ void cvt8(const float x[8], bf16x8& hi, bf16x8& lo) {
  uint_t h[4], l[4];
  #pragma unroll
  for (int p = 0; p < 4; ++p) {
    const uint_t b0 = __float_as_uint(x[2*p]);
    const uint_t b1 = __float_as_uint(x[2*p + 1]);
    // packed [bf16_trunc(x0) | bf16_trunc(x1)<<16] via one v_perm_b32
    h[p] = __builtin_amdgcn_perm(b1, b0, 0x07060302u);
    const float l0f = x[2*p]     - __uint_as_float(b0 & 0xFFFF0000u);  // exact
    const float l1f = x[2*p + 1] - __uint_as_float(b1 & 0xFFFF0000u);  // exact
    l[p] = __builtin_amdgcn_perm(__float_as_uint(l1f), __float_as_uint(l0f),
                                 0x07060302u);
  }
  hi = __builtin_bit_cast(bf16x8, make_uint4(h[0], h[1], h[2], h[3]));
  lo = __builtin_bit_cast(bf16x8, make_uint4(l[0], l[1], l[2], l[3]));
}
__device__ __forceinline__ void rd_row8(const float* M, int r, int kb, float o[8]) {
  const float* p = M + r*32;
  ld4(o,     p + ((kb)     ^ XRS(r)));
  ld4(o + 4, p + ((kb + 4) ^ XRS(r)));
}
__device__ __forceinline__ void rd_col8(const float* M, int c, int kb, float o[8]) {
  #pragma unroll
  for (int e = 0; e < 8; ++e) o[e] = M[(kb + e)*32 + (c ^ XRS(kb + e))];
}
__device__ __forceinline__ void mkfrag_row(const float* M, int r, int hoff, Frag& f) {
  float t0[8], t1[8];
  rd_row8(M, r, hoff, t0);
  rd_row8(M, r, 16 + hoff, t1);
  cvt8(t0, f.h0, f.l0);
  cvt8(t1, f.h1, f.l1);
}
__device__ __forceinline__ void mkfrag_col(const float* M, int c, int hoff, Frag& f) {
  float t0[8], t1[8];
  rd_col8(M, c, hoff, t0);
  rd_col8(M, c, 16 + hoff, t1);
  cvt8(t0, f.h0, f.l0);
  cvt8(t1, f.h1, f.l1);
}
__device__ __forceinline__ f32x16 mmacc(const Frag& A, const Frag& B, f32x16 acc) {
  acc = __builtin_amdgcn_mfma_f32_32x32x16_bf16(A.h0, B.h0, acc, 0, 0, 0);
  acc = __builtin_amdgcn_mfma_f32_32x32x16_bf16(A.h0, B.l0, acc, 0, 0, 0);
  acc = __builtin_amdgcn_mfma_f32_32x32x16_bf16(A.l0, B.h0, acc, 0, 0, 0);
  acc = __builtin_amdgcn_mfma_f32_32x32x16_bf16(A.h1, B.h1, acc, 0, 0, 0);
  acc = __builtin_amdgcn_mfma_f32_32x32x16_bf16(A.h1, B.l1, acc, 0, 0, 0);
  acc = __builtin_amdgcn_mfma_f32_32x32x16_bf16(A.l1, B.h1, acc, 0, 0, 0);
  return acc;
}
__device__ __forceinline__ f32x16 zero16() {
  f32x16 z = {0.f,0.f,0.f,0.f,0.f,0.f,0.f,0.f,0.f,0.f,0.f,0.f,0.f,0.f,0.f,0.f};
  return z;
}
__device__ __forceinline__ void st_T(float* M, int j, int ho4, const float v[16]) {
  float* p = M + j*32;
  #pragma unroll
  for (int m = 0; m < 4; ++m) st4(p + ((8*m + ho4) ^ XRS(j)), v + 4*m);
}
__device__ __forceinline__ void ld16_T(const float* M, int j, int ho4, float o[16]) {
  const float* p = M + j*32;
  #pragma unroll
  for (int m = 0; m < 4; ++m) ld4(o + 4*m, p + ((8*m + ho4) ^ XRS(j)));
}

__global__ __launch_bounds__(64) void kC9(const float* __restrict__ AS,
    const float* __restrict__ Q2, const float* __restrict__ z0,
    float* __restrict__ out) {
  __shared__ float SA[1024];   // a ; later G scratch
  __shared__ float S11[1024];  // R11^T (Phi^T after squaring)
  __shared__ float S12[1024];  // R12^T (E12^T) ; later cov buffer
  __shared__ float S22[1024];  // R22^T ; later Qd
  __shared__ float zarr[32], qds[32];
  const int b = blockIdx.x, t = threadIdx.x;
  const int j = t & 31, hh = t >> 5;
  const int hoff = hh * 8, ho4 = hh * 4;

  if (t < 32) zarr[t] = z0[(size_t)b*32 + t];
  float covreg[16];
  #pragma unroll
  for (int r = 0; r < 16; ++r) covreg[r] = 0.f;
  __syncthreads();

  float* covout = out + 3145728 + (size_t)b*24576;
  float* stout  = out + (size_t)b*768;

  for (int s = 0; s < NSEGC; ++s) {
    // ---------- init: load A, -muI, frob clamp, scale; a, t11=I, t12=0, t22=I --
    if (t < 32) qds[t] = Q2[((size_t)s*BSZ + b)*32 + t] * XSC;
    const float* asb = AS + ((size_t)s*BSZ + b)*1024;
    float av[16];
    #pragma unroll
    for (int m = 0; m < 4; ++m) ld4(av + 4*m, &asb[j*32 + 16*hh + 4*m]);
    #pragma unroll
    for (int i = 0; i < 16; ++i) if (16*hh + i == j) av[i] -= MUC;
    float ssq = 0.f;
    #pragma unroll
    for (int i = 0; i < 16; ++i) ssq += av[i]*av[i];
    #pragma unroll
    for (int off = 1; off < 64; off <<= 1) ssq += __shfl_xor(ssq, off);
    const float frob = sqrtf(ssq);
    const float sc = (frob > 3.0f ? 3.0f / (frob + 1e-6f) : 1.0f) * XSC;
    #pragma unroll
    for (int i = 0; i < 16; ++i) av[i] *= sc;
    #pragma unroll
    for (int m = 0; m < 4; ++m) {
      st4(&SA[j*32 + ((16*hh + 4*m) ^ XRS(j))], av + 4*m);
      float id[4], zo[4] = {0.f, 0.f, 0.f, 0.f};
      #pragma unroll
      for (int e = 0; e < 4; ++e) id[e] = (16*hh + 4*m + e == j) ? 1.f : 0.f;
      st4(&S11[j*32 + ((16*hh + 4*m) ^ XRS(j))], id);
      st4(&S22[j*32 + ((16*hh + 4*m) ^ XRS(j))], id);
      st4(&S12[j*32 + ((16*hh + 4*m) ^ XRS(j))], zo);
    }
    __syncthreads();
    float qv[16];
    #pragma unroll
    for (int r = 0; r < 16; ++r) qv[r] = qds[(r&3) + 8*(r>>2) + ho4];
    Frag aA, aT;
    mkfrag_row(SA, j, hoff, aA);   // A-frag of a
    mkfrag_col(SA, j, hoff, aT);   // A-frag of a^T

    // ---------- Taylor Horner ORDER=5 on X=[[a,q],[0,-a^T]] (transposed blocks)
    for (int k = 5; k >= 1; --k) {
      const float rk = 1.0f / (float)k;
      Frag Bf;
      float Xs[16];
      mkfrag_row(S11, j, hoff, Bf);
      f32x16 X = mmacc(aA, Bf, zero16());
      #pragma unroll
      for (int r = 0; r < 16; ++r) {
        const int row = (r&3) + 8*(r>>2) + ho4;
        Xs[r] = X[r]*rk + (row == j ? 1.f : 0.f);
      }
      st_T(S11, j, ho4, Xs);
      mkfrag_row(S12, j, hoff, Bf);
      X = mmacc(aA, Bf, zero16());
      float rv[16];
      ld16_T(S22, j, ho4, rv);
      #pragma unroll
      for (int r = 0; r < 16; ++r) Xs[r] = (X[r] + qv[r]*rv[r]) * rk;
      st_T(S12, j, ho4, Xs);
      mkfrag_row(S22, j, hoff, Bf);
      X = mmacc(aT, Bf, zero16());
      #pragma unroll
      for (int r = 0; r < 16; ++r) {
        const int row = (r&3) + 8*(r>>2) + ho4;
        Xs[r] = (row == j ? 1.f : 0.f) - X[r]*rk;
      }
      st_T(S22, j, ho4, Xs);
    }
    __syncthreads();

    // ---------- squaring 0: R11<-R11@R11, R12<-R11@R12+R12@R22, R22<-R22@R22 --
    {
      Frag Ac, Br;
      float Xs[16];
      mkfrag_col(S11, j, hoff, Ac);
      mkfrag_row(S11, j, hoff, Br);
      f32x16 X1 = mmacc(Ac, Br, zero16());
      #pragma unroll
      for (int r = 0; r < 16; ++r) Xs[r] = X1[r];
      st_T(S11, j, ho4, Xs);
      Frag B12; mkfrag_row(S12, j, hoff, B12);
      f32x16 X2 = mmacc(Ac, B12, zero16());
      Frag A12; mkfrag_col(S12, j, hoff, A12);
      Frag B22; mkfrag_row(S22, j, hoff, B22);
      X2 = mmacc(A12, B22, X2);
      #pragma unroll
      for (int r = 0; r < 16; ++r) Xs[r] = X2[r];
      st_T(S12, j, ho4, Xs);
      Frag A22; mkfrag_col(S22, j, hoff, A22);
      f32x16 X3 = mmacc(A22, B22, zero16());
      #pragma unroll
      for (int r = 0; r < 16; ++r) Xs[r] = X3[r];
      st_T(S22, j, ho4, Xs);
    }
    __syncthreads();
    // ---------- squaring 1: R11, R12 only (R22 not needed afterwards) --------
    {
      Frag Ac, Br;
      float Xs[16];
      mkfrag_col(S11, j, hoff, Ac);
      mkfrag_row(S11, j, hoff, Br);
      f32x16 X1 = mmacc(Ac, Br, zero16());
      Frag B12; mkfrag_row(S12, j, hoff, B12);
      f32x16 X2 = mmacc(Ac, B12, zero16());
      Frag A12; mkfrag_col(S12, j, hoff, A12);
      Frag B22; mkfrag_row(S22, j, hoff, B22);
      X2 = mmacc(A12, B22, X2);
      #pragma unroll
      for (int r = 0; r < 16; ++r) Xs[r] = X1[r];
      st_T(S11, j, ho4, Xs);
      #pragma unroll
      for (int r = 0; r < 16; ++r) Xs[r] = X2[r];
      st_T(S12, j, ho4, Xs);
    }
    __syncthreads();

    // ---------- Qd = 0.5*(Phi@E12 + (Phi@E12)^T) -> S22 ----------------------
    Frag PhiF;
    mkfrag_col(S11, j, hoff, PhiF);
    {
      Frag B12; mkfrag_row(S12, j, hoff, B12);
      f32x16 Xq = mmacc(PhiF, B12, zero16());
      float Xs[16];
      #pragma unroll
      for (int r = 0; r < 16; ++r) Xs[r] = Xq[r];
      st_T(S22, j, ho4, Xs);
      __syncthreads();
      float sym[16];
      #pragma unroll
      for (int r = 0; r < 16; ++r) {
        const int row = (r&3) + 8*(r>>2) + ho4;
        const float tv = S22[row*32 + (j ^ XRS(row))];
        sym[r] = 0.5f * (Xs[r] + tv);
      }
      __syncthreads();
      st_T(S22, j, ho4, sym);
    }
    __syncthreads();

    // ---------- stage cov (covreg, C/D order) into S12 (E12 dead) ------------
    st_T(S12, j, ho4, covreg);
    __syncthreads();

    // ---------- 8 propagation steps: cov <- Phi cov Phi^T + Qd ; z <- Phi z ---
    for (int tt = 0; tt < 8; ++tt) {
      Frag Bcov; mkfrag_row(S12, j, hoff, Bcov);
      f32x16 G = mmacc(PhiF, Bcov, zero16());
      float Gs[16];
      #pragma unroll
      for (int r = 0; r < 16; ++r) Gs[r] = G[r];
      st_T(SA, j, ho4, Gs);
      Frag AG; mkfrag_col(SA, j, hoff, AG);
      f32x16 C = mmacc(AG, PhiF, zero16());
      float qdv[16], Cs[16];
      ld16_T(S22, j, ho4, qdv);
      #pragma unroll
      for (int r = 0; r < 16; ++r) Cs[r] = C[r] + qdv[r];
      float zp = 0.f;
      #pragma unroll
      for (int e = 0; e < 16; ++e) {
        const int kr = 16*hh + e;
        zp += S11[kr*32 + (j ^ XRS(kr))] * zarr[kr];
      }
      zp += __shfl_xor(zp, 32);
      st_T(S12, j, ho4, Cs);
      #pragma unroll
      for (int r = 0; r < 16; ++r) covreg[r] = Cs[r];
      float* cb = covout + (size_t)(s*8 + tt)*1024;
      #pragma unroll
      for (int r = 0; r < 16; ++r)
        cb[((r&3) + 8*(r>>2) + ho4)*32 + j] = Cs[r];
      if (t < 32) {
        zarr[t] = zp;
        stout[(s*8 + tt)*32 + t] = zp;
      }
      __syncthreads();
    }
  }
}

// ---------------- launch ----------------
extern "C" void kernel_launch(void* const* d_in, const int* in_sizes, int n_in,
                              void* d_out, int out_size, void* d_ws, size_t ws_size,
                              hipStream_t stream) {
  const float* ctx  = (const float*)d_in[0];
  const float* z0   = (const float*)d_in[1];
  const float* S_W  = (const float*)d_in[2];
  const float* S_b  = (const float*)d_in[3];
  const float* L_W  = (const float*)d_in[4];
  const float* L_b  = (const float*)d_in[5];
  const float* G_W  = (const float*)d_in[6];
  const float* G_b  = (const float*)d_in[7];
  const float* Sg_W = (const float*)d_in[8];
  const float* Sg_b = (const float*)d_in[9];
  float* out = (float*)d_out;
  float* ws  = (float*)d_ws;

  // ws layout (f32 offsets):
  //   w_ 0 (98304) | q2 98304 (393216) | ctxT 491520 (524288)
  //   as_ 1015808 (12582912) -> 13598720
  //   phase1: panAh/panAl (8912896u) @13598720, panB3 hi/lo (6684672u) after
  //           -> ends f32 21397504 (85.6 MB)
  //   phase2: lt (fp32 8388608) ALIASES panels @13598720 -> ends 21987328 (88 MB)
  float* w_   = ws;
  float* q2   = ws + 98304;
  float* ctxT = ws + 491520;
  float* as_  = ws + 1015808;
  ushort_t* panAh  = (ushort_t*)(ws + 13598720);
  ushort_t* panAl  = panAh + 4456448;
  ushort_t* panBh3 = panAl + 4456448;
  ushort_t* panBl3 = panBh3 + 3342336;
  float* lt = ws + 13598720;

  kA   <<<dim3(4096, 3), 64,  0, stream>>>(ctx, G_W, G_b, Sg_W, Sg_b, w_, q2);
  kA2  <<<dim3(128, 4),  256, 0, stream>>>(ctx, ctxT);
  kCvtB<<<dim3(1024, 3), 256, 0, stream>>>(S_W, S_b, panBh3, panBl3);
  for (int s = 0; s < 3; ++s) {
    kCvtA<<<dim3(4096), 256, 0, stream>>>(ctx, w_, panAh, panAl, s);
    kB3  <<<dim3(8, 32), 256, 0, stream>>>(panAh, panAl,
                                           panBh3 + (size_t)s*1114112,
                                           panBl3 + (size_t)s*1114112,
                                           as_ + (size_t)s*4194304);
  }
  for (int s = 0; s < 3; ++s) {
    kL  <<<dim3(16, 32), 256, 0, stream>>>(ctxT, L_W, L_b, w_, lt, s);
    kLLT<<<dim3(1024),   128, 0, stream>>>(lt, as_, s);
  }
  kC9 <<<dim3(4096),    64, 0, stream>>>(as_, q2, z0, out);
}

// Round 11
// 608.878 us; speedup vs baseline: 2.2858x; 1.0353x over previous
//
#include <hip/hip_runtime.h>
#include <math.h>

// TVKoopmanMoE: B=4096, C=128, D=32, K=8, R=8, NSEG=3, STEPS=8 each, DT=0.1
//  - kA: gates w (softmax) + diag^2
//  - AS GEMM via MFMA bf16 hi/lo split (kCvtA/kCvtB/kB3), bias folded via K-ext
//  - kL3: Ltil GEMM via MFMA hi/lo (kB3 skeleton, K=128, NITER=6), epilogue
//    (acc+Lb)*sqrt(w); writes the SAME lt layout as old kL -> kLLT unchanged.
//  - kLLT: AS -= Ltil Ltil^T (unchanged)
//  - kC10: ONE WAVE per b expm+propagation. R10's kC9 with SA eliminated:
//    'a' staged through S12 pre-init; propagation G-scratch in S11 (Phi lives
//    in PhiF registers); z-dot from PhiF hi+lo. 3 LDS buffers = 12.5 KB ->
//    12 blocks/CU (was 9). __launch_bounds__(64,3) caps VGPR at 170.

#define NSEGC 3
#define BSZ   4096
#define MUC   0.14861455999447191f   /* -ln(0.7)/(0.1*24) */
#define XSC   0.025f                 /* DT / 2^SQ = 0.1/4 */
#define XRS(r) (((r) & 7) << 2)

typedef unsigned short ushort_t;
typedef unsigned int uint_t;
typedef __attribute__((ext_vector_type(8))) short bf16x8;
typedef __attribute__((ext_vector_type(16))) float f32x16;

__device__ __forceinline__ void ld4(float d[4], const float* p) {
  const float4 v = *(const float4*)p; d[0]=v.x; d[1]=v.y; d[2]=v.z; d[3]=v.w;
}
__device__ __forceinline__ void st4(float* p, const float d[4]) {
  *(float4*)p = make_float4(d[0], d[1], d[2], d[3]);
}
__device__ __forceinline__ unsigned short bf_rne(float x) {
  unsigned b = __float_as_uint(x);
  unsigned r = b + 0x7FFFu + ((b >> 16) & 1u);
  return (unsigned short)(r >> 16);
}
__device__ __forceinline__ float bf2f(short v) {
  return __uint_as_float(((uint_t)(unsigned short)v) << 16);
}

// ---------------- kA: gates (softmax(logits/2)) and diag^2 ----------------
__global__ __launch_bounds__(64) void kA(const float* __restrict__ ctx,
    const float* __restrict__ GW, const float* __restrict__ Gb,
    const float* __restrict__ SgW, const float* __restrict__ Sgb,
    float* __restrict__ Wsm, float* __restrict__ Q2) {
  const int b = blockIdx.x, s = blockIdx.y, l = threadIdx.x;
  __shared__ float c[128];
  c[l]      = ctx[(size_t)b*128 + l];
  c[l + 64] = ctx[(size_t)b*128 + 64 + l];
  __syncthreads();
  if (l < 8) {
    float acc = Gb[s*8 + l];
    #pragma unroll 4
    for (int q = 0; q < 128; ++q) acc += c[q] * GW[(size_t)(s*128 + q)*8 + l];
    float li = acc * 0.5f;            // / TEMP (=2)
    float m = li;
    m = fmaxf(m, __shfl_xor(m, 1));
    m = fmaxf(m, __shfl_xor(m, 2));
    m = fmaxf(m, __shfl_xor(m, 4));
    float e = expf(li - m);
    float sum = e;
    sum += __shfl_xor(sum, 1);
    sum += __shfl_xor(sum, 2);
    sum += __shfl_xor(sum, 4);
    Wsm[((size_t)s*BSZ + b)*8 + l] = e / sum;
  } else if (l < 40) {
    const int d = l - 8;
    float acc = Sgb[s*32 + d];
    #pragma unroll 4
    for (int q = 0; q < 128; ++q) acc += c[q] * SgW[(size_t)(s*128 + q)*32 + d];
    float sp = fmaxf(acc, 0.f) + log1pf(expf(-fabsf(acc)));  // stable softplus
    float dg = fminf(sp, 1.0f);
    Q2[((size_t)s*BSZ + b)*32 + d] = dg * dg;
  }
}

// -------- kCvtX: ctx -> hi/lo bf16 panels [4096][128] ----------------------
__global__ __launch_bounds__(256) void kCvtX(const float* __restrict__ ctx,
    ushort_t* __restrict__ Xh, ushort_t* __restrict__ Xl) {
  const int idx = blockIdx.x*256 + threadIdx.x;
  const float v = ctx[idx];
  const unsigned short h = bf_rne(v);
  Xh[idx] = h;
  Xl[idx] = bf_rne(v - __uint_as_float(((unsigned)h) << 16));
}

// -------- kCvtL: lwT[s][n][c] = L_W[s][c][n] hi/lo bf16 --------------------
__global__ __launch_bounds__(256) void kCvtL(const float* __restrict__ LW,
    ushort_t* __restrict__ Lh, ushort_t* __restrict__ Ll) {
  __shared__ float tile[32][33];
  const int nb = blockIdx.x * 32, cb = blockIdx.y * 32, s = blockIdx.z;
  const int tx = threadIdx.x & 31, ty = threadIdx.x >> 5;
  for (int r = ty; r < 32; r += 8)
    tile[r][tx] = LW[((size_t)(s*128 + cb + r))*2048 + nb + tx];
  __syncthreads();
  for (int r = ty; r < 32; r += 8) {
    const float v = tile[tx][r];          // LW[cb+tx][nb+r]
    const unsigned short h = bf_rne(v);
    const size_t o = ((size_t)s*2048 + nb + r)*128 + cb + tx;
    Lh[o] = h;
    Ll[o] = bf_rne(v - __uint_as_float(((unsigned)h) << 16));
  }
}

// -------- kCvtA: A'[b][kc] hi/lo bf16; kc<1024: w[k]*ctx[c]; 1024..1031: w; pad 0
__global__ __launch_bounds__(256) void kCvtA(const float* __restrict__ ctx,
    const float* __restrict__ Wsm, ushort_t* __restrict__ Ah,
    ushort_t* __restrict__ Al, int s) {
  __shared__ float cs[128];
  __shared__ float wwv[8];
  const int b = blockIdx.x, t = threadIdx.x;
  if (t < 128) cs[t] = ctx[(size_t)b*128 + t];
  else if (t < 136) wwv[t - 128] = Wsm[((size_t)s*BSZ + b)*8 + (t - 128)];
  __syncthreads();
  for (int kc = t; kc < 1088; kc += 256) {
    float v = 0.f;
    if (kc < 1024) v = wwv[kc >> 7] * cs[kc & 127];
    else if (kc < 1032) v = wwv[kc - 1024];
    const unsigned short h = bf_rne(v);
    const float hf = __uint_as_float(((unsigned)h) << 16);
    Ah[(size_t)b*1088 + kc] = h;
    Al[(size_t)b*1088 + kc] = bf_rne(v - hf);
  }
}

// -------- kCvtB: B'[s][n][kc] = V2^T hi/lo bf16 (all 3 segments) -----------
__global__ __launch_bounds__(256) void kCvtB(const float* __restrict__ SW,
    const float* __restrict__ Sb, ushort_t* __restrict__ Bh,
    ushort_t* __restrict__ Bl) {
  const int n = blockIdx.x, s = blockIdx.y, t = threadIdx.x;
  const int i = n >> 5, j = n & 31, nT = j*32 + i;
  ushort_t* bh = Bh + (size_t)s*1114112;
  ushort_t* bl = Bl + (size_t)s*1114112;
  for (int kc = t; kc < 1088; kc += 256) {
    float v = 0.f;
    if (kc < 1024) {
      const int k = kc >> 7, c = kc & 127;
      const float* base = SW + ((size_t)(s*128 + c))*8192 + (size_t)k*1024;
      v = base[n] - base[nT];
    } else if (kc < 1032) {
      const int k = kc - 1024;
      const float* base = Sb + (size_t)s*8192 + (size_t)k*1024;
      v = base[n] - base[nT];
    }
    const unsigned short h = bf_rne(v);
    const float hf = __uint_as_float(((unsigned)h) << 16);
    bh[(size_t)n*1088 + kc] = h;
    bl[(size_t)n*1088 + kc] = bf_rne(v - hf);
  }
}

// -------- kB3: AS_seg = A' @ B'^T via 32x32x16 bf16 MFMA, 3-product hi/lo ----
__global__ __launch_bounds__(256) void kB3(const ushort_t* __restrict__ Ah,
    const ushort_t* __restrict__ Al, const ushort_t* __restrict__ Bh,
    const ushort_t* __restrict__ Bl, float* __restrict__ ASseg) {
  __shared__ ushort_t sArr[2][2][8192];   // [buf][A/B][128 rows x 64 cols]
  const int t = threadIdx.x;
  const int l = t & 63, w = t >> 6;
  const int hh = l >> 5, lane31 = l & 31;
  const int nb = blockIdx.x * 128, bb = blockIdx.y * 128;
  const int wr0 = (w & 1) * 64, wc0 = (w >> 1) * 64;

  const ushort_t* APT[3] = {Ah, Ah, Al};
  const ushort_t* BPT[3] = {Bh, Bl, Bh};

  f32x16 acc[2][2];
  #pragma unroll
  for (int a = 0; a < 2; ++a)
    #pragma unroll
    for (int bq = 0; bq < 2; ++bq)
      #pragma unroll
      for (int e = 0; e < 16; ++e) acc[a][bq][e] = 0.f;

  #define STAGE(buf, it) do {                                                  \
    const int p_ = (it) / 17, ks_ = (it) - p_*17;                              \
    const ushort_t* As_ = APT[p_];                                             \
    const ushort_t* Bs_ = BPT[p_];                                             \
    _Pragma("unroll")                                                          \
    for (int i_ = 0; i_ < 4; ++i_) {                                           \
      const int gidx_ = i_*256 + t;                                            \
      const int r_ = gidx_ >> 3, g_ = gidx_ & 7;                               \
      const int gs_ = g_ ^ (r_ & 7);                                           \
      const ushort_t* srcA_ = As_ + (size_t)(bb + r_)*1088 + ks_*64 + gs_*8;   \
      const ushort_t* srcB_ = Bs_ + (size_t)(nb + r_)*1088 + ks_*64 + gs_*8;   \
      __builtin_amdgcn_global_load_lds(                                        \
        (const __attribute__((address_space(1))) unsigned int*)srcA_,          \
        (__attribute__((address_space(3))) unsigned int*)&sArr[buf][0][(i_*256 + w*64)*8], \
        16, 0, 0);                                                             \
      __builtin_amdgcn_global_load_lds(                                        \
        (const __attribute__((address_space(1))) unsigned int*)srcB_,          \
        (__attribute__((address_space(3))) unsigned int*)&sArr[buf][1][(i_*256 + w*64)*8], \
        16, 0, 0);                                                             \
    }                                                                          \
  } while (0)

  STAGE(0, 0);
  int cur = 0;
  #pragma unroll 1
  for (int it = 0; it < 51; ++it) {
    __syncthreads();                      // drain loads into buf[cur]
    if (it + 1 < 51) STAGE(cur ^ 1, it + 1);
    const ushort_t* lA = &sArr[cur][0][0];
    const ushort_t* lB = &sArr[cur][1][0];
    #pragma unroll
    for (int kc = 0; kc < 4; ++kc) {
      bf16x8 af[2], bfr[2];
      #pragma unroll
      for (int rt = 0; rt < 2; ++rt) {
        const int row = wr0 + rt*32 + lane31;
        const int slot = (kc*2 + hh) ^ (row & 7);
        af[rt] = *(const bf16x8*)&lA[row*64 + slot*8];
      }
      #pragma unroll
      for (int ct = 0; ct < 2; ++ct) {
        const int row = wc0 + ct*32 + lane31;
        const int slot = (kc*2 + hh) ^ (row & 7);
        bfr[ct] = *(const bf16x8*)&lB[row*64 + slot*8];
      }
      #pragma unroll
      for (int rt = 0; rt < 2; ++rt)
        #pragma unroll
        for (int ct = 0; ct < 2; ++ct)
          acc[rt][ct] = __builtin_amdgcn_mfma_f32_32x32x16_bf16(
              af[rt], bfr[ct], acc[rt][ct], 0, 0, 0);
    }
    cur ^= 1;
  }
  #undef STAGE

  #pragma unroll
  for (int rt = 0; rt < 2; ++rt)
    #pragma unroll
    for (int ct = 0; ct < 2; ++ct) {
      float* o = ASseg + ((size_t)(bb + wr0 + rt*32))*1024 + nb + wc0 + ct*32 + lane31;
      #pragma unroll
      for (int reg = 0; reg < 16; ++reg) {
        const int row = (reg & 3) + 8*(reg >> 2) + 4*hh;
        o[(size_t)row*1024] = acc[rt][ct][reg];
      }
    }
}

// -------- kL3: lt = (ctx @ L_W + Lb)*sqrt(w) via MFMA hi/lo (K=128) --------
// Writes the SAME lt layout as old kL: lt[b][kidx*256 + r*32 + dcol].
__global__ __launch_bounds__(256) void kL3(const ushort_t* __restrict__ Xh,
    const ushort_t* __restrict__ Xl, const ushort_t* __restrict__ Lh,
    const ushort_t* __restrict__ Ll, const float* __restrict__ Lb,
    const float* __restrict__ Wsm, float* __restrict__ lt, int s) {
  __shared__ ushort_t sArr[2][2][8192];
  __shared__ float sqw[128][8];
  const int t = threadIdx.x;
  const int l = t & 63, w = t >> 6;
  const int hh = l >> 5, lane31 = l & 31;
  const int nb = blockIdx.x * 128, bb = blockIdx.y * 128;
  const int wr0 = (w & 1) * 64, wc0 = (w >> 1) * 64;
  for (int i = t; i < 1024; i += 256)
    sqw[i >> 3][i & 7] = sqrtf(Wsm[((size_t)s*BSZ + bb + (i >> 3))*8 + (i & 7)]);

  const ushort_t* APT[3] = {Xh, Xh, Xl};
  const ushort_t* BPT[3] = {Lh + (size_t)s*262144, Ll + (size_t)s*262144,
                            Lh + (size_t)s*262144};

  f32x16 acc[2][2];
  #pragma unroll
  for (int a = 0; a < 2; ++a)
    #pragma unroll
    for (int bq = 0; bq < 2; ++bq)
      #pragma unroll
      for (int e = 0; e < 16; ++e) acc[a][bq][e] = 0.f;

  #define STAGEL(buf, it) do {                                                 \
    const int p_ = (it) >> 1, ks_ = (it) & 1;                                  \
    const ushort_t* As_ = APT[p_];                                             \
    const ushort_t* Bs_ = BPT[p_];                                             \
    _Pragma("unroll")                                                          \
    for (int i_ = 0; i_ < 4; ++i_) {                                           \
      const int gidx_ = i_*256 + t;                                            \
      const int r_ = gidx_ >> 3, g_ = gidx_ & 7;                               \
      const int gs_ = g_ ^ (r_ & 7);                                           \
      const ushort_t* srcA_ = As_ + (size_t)(bb + r_)*128 + ks_*64 + gs_*8;    \
      const ushort_t* srcB_ = Bs_ + (size_t)(nb + r_)*128 + ks_*64 + gs_*8;    \
      __builtin_amdgcn_global_load_lds(                                        \
        (const __attribute__((address_space(1))) unsigned int*)srcA_,          \
        (__attribute__((address_space(3))) unsigned int*)&sArr[buf][0][(i_*256 + w*64)*8], \
        16, 0, 0);                                                             \
      __builtin_amdgcn_global_load_lds(                                        \
        (const __attribute__((address_space(1))) unsigned int*)srcB_,          \
        (__attribute__((address_space(3))) unsigned int*)&sArr[buf][1][(i_*256 + w*64)*8], \
        16, 0, 0);                                                             \
    }                                                                          \
  } while (0)

  STAGEL(0, 0);
  int cur = 0;
  #pragma unroll 1
  for (int it = 0; it < 6; ++it) {
    __syncthreads();
    if (it + 1 < 6) STAGEL(cur ^ 1, it + 1);
    const ushort_t* lA = &sArr[cur][0][0];
    const ushort_t* lB = &sArr[cur][1][0];
    #pragma unroll
    for (int kc = 0; kc < 4; ++kc) {
      bf16x8 af[2], bfr[2];
      #pragma unroll
      for (int rt = 0; rt < 2; ++rt) {
        const int row = wr0 + rt*32 + lane31;
        const int slot = (kc*2 + hh) ^ (row & 7);
        af[rt] = *(const bf16x8*)&lA[row*64 + slot*8];
      }
      #pragma unroll
      for (int ct = 0; ct < 2; ++ct) {
        const int row = wc0 + ct*32 + lane31;
        const int slot = (kc*2 + hh) ^ (row & 7);
        bfr[ct] = *(const bf16x8*)&lB[row*64 + slot*8];
      }
      #pragma unroll
      for (int rt = 0; rt < 2; ++rt)
        #pragma unroll
        for (int ct = 0; ct < 2; ++ct)
          acc[rt][ct] = __builtin_amdgcn_mfma_f32_32x32x16_bf16(
              af[rt], bfr[ct], acc[rt][ct], 0, 0, 0);
    }
    cur ^= 1;
  }
  #undef STAGEL

  // epilogue: (acc + Lb[n]) * sqrt(w[b][n>>8]) -> lt[b][ltcol(n)]
  #pragma unroll
  for (int rt = 0; rt < 2; ++rt)
    #pragma unroll
    for (int ct = 0; ct < 2; ++ct) {
      const int n = nb + wc0 + ct*32 + lane31;
      const float lb = Lb[(size_t)s*2048 + n];
      const int kidx = n >> 8;
      const int ltcol = (kidx << 8) + ((n & 7) << 5) + ((n >> 3) & 31);
      #pragma unroll
      for (int reg = 0; reg < 16; ++reg) {
        const int lrow = wr0 + rt*32 + (reg & 3) + 8*(reg >> 2) + 4*hh;
        lt[(size_t)(bb + lrow)*2048 + ltcol] =
            (acc[rt][ct][reg] + lb) * sqw[lrow][kidx];
      }
    }
}

// ---------------- kLLT: AS -= Ltil Ltil^T  (4 b per block) ----------------
__global__ __launch_bounds__(128) void kLLT(const float* __restrict__ LT,
                                            float* __restrict__ AS, int s) {
  __shared__ float L4[4][64][32];
  const int t = threadIdx.x;
  const int bbase = blockIdx.x * 4;
  {
    float* l4f = &L4[0][0][0];
    const float* src = LT + (size_t)bbase * 2048;
    for (int i = t*4; i < 8192; i += 512)
      *(float4*)&l4f[i] = *(const float4*)&src[i];
  }
  __syncthreads();
  const int b = t >> 5, u = t & 31;
  const int i0 = (u >> 2) * 4, j0 = (u & 3) * 8;
  float acc[4][8] = {};
  #pragma unroll 8
  for (int kr = 0; kr < 64; ++kr) {
    float pa[4], pb[8];
    ld4(pa, &L4[b][kr][i0]);
    ld4(pb, &L4[b][kr][j0]); ld4(pb + 4, &L4[b][kr][j0 + 4]);
    #pragma unroll
    for (int ii = 0; ii < 4; ++ii)
      #pragma unroll
      for (int jj = 0; jj < 8; ++jj) acc[ii][jj] += pa[ii] * pb[jj];
  }
  float* dst = AS + ((size_t)s*BSZ + bbase + b)*1024;
  for (int ii = 0; ii < 4; ++ii) {
    float x[8];
    ld4(x, &dst[(i0+ii)*32 + j0]); ld4(x + 4, &dst[(i0+ii)*32 + j0 + 4]);
    #pragma unroll
    for (int jj = 0; jj < 8; ++jj) x[jj] -= acc[ii][jj];
    st4(&dst[(i0+ii)*32 + j0], x); st4(&dst[(i0+ii)*32 + j0 + 4], &x[4]);
  }
}

// ================= kC10: MFMA hi/lo expm + propagation, one wave per b ========
// 3 LDS buffers (S11,S12,S22). 'a' staged through S12 pre-init; propagation
// G-scratch in S11 (Phi persists in PhiF registers); z-dot from PhiF hi+lo.
struct Frag { bf16x8 h0, l0, h1, l1; };

__device__ __forceinline__ void cvt8(const float x[8], bf16x8& hi, bf16x8& lo) {
  uint_t h[4], l[4];
  #pragma unroll
  for (int p = 0; p < 4; ++p) {
    const uint_t b0 = __float_as_uint(x[2*p]);
    const uint_t b1 = __float_as_uint(x[2*p + 1]);
    h[p] = __builtin_amdgcn_perm(b1, b0, 0x07060302u);
    const float l0f = x[2*p]     - __uint_as_float(b0 & 0xFFFF0000u);  // exact
    const float l1f = x[2*p + 1] - __uint_as_float(b1 & 0xFFFF0000u);  // exact
    l[p] = __builtin_amdgcn_perm(__float_as_uint(l1f), __float_as_uint(l0f),
                                 0x07060302u);
  }
  hi = __builtin_bit_cast(bf16x8, make_uint4(h[0], h[1], h[2], h[3]));
  lo = __builtin_bit_cast(bf16x8, make_uint4(l[0], l[1], l[2], l[3]));
}
__device__ __forceinline__ void rd_row8(const float* M, int r, int kb, float o[8]) {
  const float* p = M + r*32;
  ld4(o,     p + ((kb)     ^ XRS(r)));
  ld4(o + 4, p + ((kb + 4) ^ XRS(r)));
}
__device__ __forceinline__ void rd_col8(const float* M, int c, int kb, float o[8]) {
  #pragma unroll
  for (int e = 0; e < 8; ++e) o[e] = M[(kb + e)*32 + (c ^ XRS(kb + e))];
}
__device__ __forceinline__ void mkfrag_row(const float* M, int r, int hoff, Frag& f) {
  float t0[8], t1[8];
  rd_row8(M, r, hoff, t0);
  rd_row8(M, r, 16 + hoff, t1);
  cvt8(t0, f.h0, f.l0);
  cvt8(t1, f.h1, f.l1);
}
__device__ __forceinline__ void mkfrag_col(const float* M, int c, int hoff, Frag& f) {
  float t0[8], t1[8];
  rd_col8(M, c, hoff, t0);
  rd_col8(M, c, 16 + hoff, t1);
  cvt8(t0, f.h0, f.l0);
  cvt8(t1, f.h1, f.l1);
}
__device__ __forceinline__ f32x16 mmacc(const Frag& A, const Frag& B, f32x16 acc) {
  acc = __builtin_amdgcn_mfma_f32_32x32x16_bf16(A.h0, B.h0, acc, 0, 0, 0);
  acc = __builtin_amdgcn_mfma_f32_32x32x16_bf16(A.h0, B.l0, acc, 0, 0, 0);
  acc = __builtin_amdgcn_mfma_f32_32x32x16_bf16(A.l0, B.h0, acc, 0, 0, 0);
  acc = __builtin_amdgcn_mfma_f32_32x32x16_bf16(A.h1, B.h1, acc, 0, 0, 0);
  acc = __builtin_amdgcn_mfma_f32_32x32x16_bf16(A.h1, B.l1, acc, 0, 0, 0);
  acc = __builtin_amdgcn_mfma_f32_32x32x16_bf16(A.l1, B.h1, acc, 0, 0, 0);
  return acc;
}
__device__ __forceinline__ f32x16 zero16() {
  f32x16 z = {0.f,0.f,0.f,0.f,0.f,0.f,0.f,0.f,0.f,0.f,0.f,0.f,0.f,0.f,0.f,0.f};
  return z;
}
__device__ __forceinline__ void st_T(float* M, int j, int ho4, const float v[16]) {
  float* p = M + j*32;
  #pragma unroll
  for (int m = 0; m < 4; ++m) st4(p + ((8*m + ho4) ^ XRS(j)), v + 4*m);
}
__device__ __forceinline__ void ld16_T(const float* M, int j, int ho4, float o[16]) {
  const float* p = M + j*32;
  #pragma unroll
  for (int m = 0; m < 4; ++m) ld4(o + 4*m, p + ((8*m + ho4) ^ XRS(j)));
}

__global__ __launch_bounds__(64, 3) void kC10(const float* __restrict__ AS,
    const float* __restrict__ Q2, const float* __restrict__ z0,
    float* __restrict__ out) {
  __shared__ float S11[1024];  // R11^T (Phi^T) ; G scratch in propagation
  __shared__ float S12[1024];  // a staging; R12^T (E12^T); cov buffer
  __shared__ float S22[1024];  // R22^T ; later Qd
  __shared__ float zarr[32], qds[32];
  const int b = blockIdx.x, t = threadIdx.x;
  const int j = t & 31, hh = t >> 5;
  const int hoff = hh * 8, ho4 = hh * 4;

  if (t < 32) zarr[t] = z0[(size_t)b*32 + t];
  float covreg[16];
  #pragma unroll
  for (int r = 0; r < 16; ++r) covreg[r] = 0.f;
  __syncthreads();

  float* covout = out + 3145728 + (size_t)b*24576;
  float* stout  = out + (size_t)b*768;

  for (int s = 0; s < NSEGC; ++s) {
    // ---------- init: load A, -muI, frob clamp, scale; stage a via S12 -------
    if (t < 32) qds[t] = Q2[((size_t)s*BSZ + b)*32 + t] * XSC;
    const float* asb = AS + ((size_t)s*BSZ + b)*1024;
    float av[16];
    #pragma unroll
    for (int m = 0; m < 4; ++m) ld4(av + 4*m, &asb[j*32 + 16*hh + 4*m]);
    #pragma unroll
    for (int i = 0; i < 16; ++i) if (16*hh + i == j) av[i] -= MUC;
    float ssq = 0.f;
    #pragma unroll
    for (int i = 0; i < 16; ++i) ssq += av[i]*av[i];
    #pragma unroll
    for (int off = 1; off < 64; off <<= 1) ssq += __shfl_xor(ssq, off);
    const float frob = sqrtf(ssq);
    const float sc = (frob > 3.0f ? 3.0f / (frob + 1e-6f) : 1.0f) * XSC;
    #pragma unroll
    for (int i = 0; i < 16; ++i) av[i] *= sc;
    __syncthreads();
    #pragma unroll
    for (int m = 0; m < 4; ++m)
      st4(&S12[j*32 + ((16*hh + 4*m) ^ XRS(j))], av + 4*m);  // S12 = a (rows)
    __syncthreads();
    Frag aA, aT;
    mkfrag_row(S12, j, hoff, aA);   // A-frag of a
    mkfrag_col(S12, j, hoff, aT);   // A-frag of a^T
    __syncthreads();
    #pragma unroll
    for (int m = 0; m < 4; ++m) {
      float id[4], zo[4] = {0.f, 0.f, 0.f, 0.f};
      #pragma unroll
      for (int e = 0; e < 4; ++e) id[e] = (16*hh + 4*m + e == j) ? 1.f : 0.f;
      st4(&S11[j*32 + ((16*hh + 4*m) ^ XRS(j))], id);
      st4(&S22[j*32 + ((16*hh + 4*m) ^ XRS(j))], id);
      st4(&S12[j*32 + ((16*hh + 4*m) ^ XRS(j))], zo);
    }
    __syncthreads();
    float qv[16];
    #pragma unroll
    for (int r = 0; r < 16; ++r) qv[r] = qds[(r&3) + 8*(r>>2) + ho4];

    // ---------- Taylor Horner ORDER=5 on X=[[a,q],[0,-a^T]] (transposed blocks)
    for (int k = 5; k >= 1; --k) {
      const float rk = 1.0f / (float)k;
      Frag Bf;
      float Xs[16];
      mkfrag_row(S11, j, hoff, Bf);
      f32x16 X = mmacc(aA, Bf, zero16());
      #pragma unroll
      for (int r = 0; r < 16; ++r) {
        const int row = (r&3) + 8*(r>>2) + ho4;
        Xs[r] = X[r]*rk + (row == j ? 1.f : 0.f);
      }
      st_T(S11, j, ho4, Xs);
      mkfrag_row(S12, j, hoff, Bf);
      X = mmacc(aA, Bf, zero16());
      float rv[16];
      ld16_T(S22, j, ho4, rv);
      #pragma unroll
      for (int r = 0; r < 16; ++r) Xs[r] = (X[r] + qv[r]*rv[r]) * rk;
      st_T(S12, j, ho4, Xs);
      mkfrag_row(S22, j, hoff, Bf);
      X = mmacc(aT, Bf, zero16());
      #pragma unroll
      for (int r = 0; r < 16; ++r) {
        const int row = (r&3) + 8*(r>>2) + ho4;
        Xs[r] = (row == j ? 1.f : 0.f) - X[r]*rk;
      }
      st_T(S22, j, ho4, Xs);
    }
    __syncthreads();

    // ---------- squaring 0 ----------
    {
      Frag Ac, Br;
      float Xs[16];
      mkfrag_col(S11, j, hoff, Ac);
      mkfrag_row(S11, j, hoff, Br);
      f32x16 X1 = mmacc(Ac, Br, zero16());
      #pragma unroll
      for (int r = 0; r < 16; ++r) Xs[r] = X1[r];
      st_T(S11, j, ho4, Xs);
      Frag B12; mkfrag_row(S12, j, hoff, B12);
      f32x16 X2 = mmacc(Ac, B12, zero16());
      Frag A12; mkfrag_col(S12, j, hoff, A12);
      Frag B22; mkfrag_row(S22, j, hoff, B22);
      X2 = mmacc(A12, B22, X2);
      #pragma unroll
      for (int r = 0; r < 16; ++r) Xs[r] = X2[r];
      st_T(S12, j, ho4, Xs);
      Frag A22; mkfrag_col(S22, j, hoff, A22);
      f32x16 X3 = mmacc(A22, B22, zero16());
      #pragma unroll
      for (int r = 0; r < 16; ++r) Xs[r] = X3[r];
      st_T(S22, j, ho4, Xs);
    }
    __syncthreads();
    // ---------- squaring 1: R11, R12 only ----------
    {
      Frag Ac, Br;
      float Xs[16];
      mkfrag_col(S11, j, hoff, Ac);
      mkfrag_row(S11, j, hoff, Br);
      f32x16 X1 = mmacc(Ac, Br, zero16());
      Frag B12; mkfrag_row(S12, j, hoff, B12);
      f32x16 X2 = mmacc(Ac, B12, zero16());
      Frag A12; mkfrag_col(S12, j, hoff, A12);
      Frag B22; mkfrag_row(S22, j, hoff, B22);
      X2 = mmacc(A12, B22, X2);
      #pragma unroll
      for (int r = 0; r < 16; ++r) Xs[r] = X1[r];
      st_T(S11, j, ho4, Xs);
      #pragma unroll
      for (int r = 0; r < 16; ++r) Xs[r] = X2[r];
      st_T(S12, j, ho4, Xs);
    }
    __syncthreads();

    // ---------- Qd = 0.5*(Phi@E12 + (Phi@E12)^T) -> S22 ----------
    Frag PhiF;
    mkfrag_col(S11, j, hoff, PhiF);   // lane j holds Phi[j][hoff+e], [16+hoff+e]
    {
      Frag B12; mkfrag_row(S12, j, hoff, B12);
      f32x16 Xq = mmacc(PhiF, B12, zero16());
      float Xs[16];
      #pragma unroll
      for (int r = 0; r < 16; ++r) Xs[r] = Xq[r];
      st_T(S22, j, ho4, Xs);
      __syncthreads();
      float sym[16];
      #pragma unroll
      for (int r = 0; r < 16; ++r) {
        const int row = (r&3) + 8*(r>>2) + ho4;
        const float tv = S22[row*32 + (j ^ XRS(row))];
        sym[r] = 0.5f * (Xs[r] + tv);
      }
      __syncthreads();
      st_T(S22, j, ho4, sym);
    }
    __syncthreads();

    // ---------- stage cov (covreg, C/D order) into S12 (E12 dead) ------------
    st_T(S12, j, ho4, covreg);
    __syncthreads();

    // ---------- 8 propagation steps: cov <- Phi cov Phi^T + Qd ; z <- Phi z ---
    for (int tt = 0; tt < 8; ++tt) {
      Frag Bcov; mkfrag_row(S12, j, hoff, Bcov);
      f32x16 G = mmacc(PhiF, Bcov, zero16());
      float Gs[16];
      #pragma unroll
      for (int r = 0; r < 16; ++r) Gs[r] = G[r];
      st_T(S11, j, ho4, Gs);                         // S11 = G^T (Phi in regs)
      Frag AG; mkfrag_col(S11, j, hoff, AG);
      f32x16 C = mmacc(AG, PhiF, zero16());
      float qdv[16], Cs[16];
      ld16_T(S22, j, ho4, qdv);
      #pragma unroll
      for (int r = 0; r < 16; ++r) Cs[r] = C[r] + qdv[r];
      // z' = Phi@z from PhiF registers (hi+lo reconstruction)
      float zp = 0.f;
      #pragma unroll
      for (int e = 0; e < 8; ++e) {
        zp += (bf2f(PhiF.h0[e]) + bf2f(PhiF.l0[e])) * zarr[hoff + e];
        zp += (bf2f(PhiF.h1[e]) + bf2f(PhiF.l1[e])) * zarr[16 + hoff + e];
      }
      zp += __shfl_xor(zp, 32);
      st_T(S12, j, ho4, Cs);
      #pragma unroll
      for (int r = 0; r < 16; ++r) covreg[r] = Cs[r];
      float* cb = covout + (size_t)(s*8 + tt)*1024;
      #pragma unroll
      for (int r = 0; r < 16; ++r)
        cb[((r&3) + 8*(r>>2) + ho4)*32 + j] = Cs[r];
      if (t < 32) {
        zarr[t] = zp;
        stout[(s*8 + tt)*32 + t] = zp;
      }
      __syncthreads();
    }
  }
}

// ---------------- launch ----------------
extern "C" void kernel_launch(void* const* d_in, const int* in_sizes, int n_in,
                              void* d_out, int out_size, void* d_ws, size_t ws_size,
                              hipStream_t stream) {
  const float* ctx  = (const float*)d_in[0];
  const float* z0   = (const float*)d_in[1];
  const float* S_W  = (const float*)d_in[2];
  const float* S_b  = (const float*)d_in[3];
  const float* L_W  = (const float*)d_in[4];
  const float* L_b  = (const float*)d_in[5];
  const float* G_W  = (const float*)d_in[6];
  const float* G_b  = (const float*)d_in[7];
  const float* Sg_W = (const float*)d_in[8];
  const float* Sg_b = (const float*)d_in[9];
  float* out = (float*)d_out;
  float* ws  = (float*)d_ws;

  // ws layout (f32 offsets):
  //   w_ 0 | q2 98304 | as_ 1015808 (12.6M f32) -> 13598720
  //   phase1 panels (ushort) @13598720: Ah/Al 8.9Mu, Bh3/Bl3 6.7Mu -> f32 21397504
  //   lt (f32, 8.4M) ALIASES phase1 panels @13598720 -> ends 21987328
  //   cx/lwT panels (ushort) @21987328: 2.62Mu -> ends f32 23298048 (93.2 MB)
  float* w_   = ws;
  float* q2   = ws + 98304;
  float* as_  = ws + 1015808;
  ushort_t* panAh  = (ushort_t*)(ws + 13598720);
  ushort_t* panAl  = panAh + 4456448;
  ushort_t* panBh3 = panAl + 4456448;
  ushort_t* panBl3 = panBh3 + 3342336;
  float* lt = ws + 13598720;
  ushort_t* cxh = (ushort_t*)(ws + 21987328);
  ushort_t* cxl = cxh + 524288;
  ushort_t* lwh = cxl + 524288;
  ushort_t* lwl = lwh + 786432;

  kA   <<<dim3(4096, 3), 64,  0, stream>>>(ctx, G_W, G_b, Sg_W, Sg_b, w_, q2);
  kCvtX<<<dim3(2048),    256, 0, stream>>>(ctx, cxh, cxl);
  kCvtL<<<dim3(64, 4, 3),256, 0, stream>>>(L_W, lwh, lwl);
  kCvtB<<<dim3(1024, 3), 256, 0, stream>>>(S_W, S_b, panBh3, panBl3);
  for (int s = 0; s < 3; ++s) {
    kCvtA<<<dim3(4096), 256, 0, stream>>>(ctx, w_, panAh, panAl, s);
    kB3  <<<dim3(8, 32), 256, 0, stream>>>(panAh, panAl,
                                           panBh3 + (size_t)s*1114112,
                                           panBl3 + (size_t)s*1114112,
                                           as_ + (size_t)s*4194304);
  }
  for (int s = 0; s < 3; ++s) {
    kL3 <<<dim3(16, 32), 256, 0, stream>>>(cxh, cxl, lwh, lwl, L_b, w_, lt, s);
    kLLT<<<dim3(1024),   128, 0, stream>>>(lt, as_, s);
  }
  kC10<<<dim3(4096),    64, 0, stream>>>(as_, q2, z0, out);
}